// Round 12
// baseline (1973.191 us; speedup 1.0000x reference)
//
#include <hip/hip_runtime.h>
#include <hip/hip_bf16.h>
#include <math.h>

#define M_  4
#define N_  50000
#define E_  400000
#define IN_ 128
#define C_  128
#define HID_ 256

// ---------------------------------------------------------------------------
// Tiled f32 GEMM: 64 rows x 128 cols, 256 threads, 4x8 micro, BK=8.
// B staged in LDS (prefetched, 2 barriers/tile). A is NOT staged: each
// thread loads its 4 fragment rows directly from global — the 16 tx-threads
// of a wave issue identical addresses (hardware broadcast-merge), and A
// panels are L2-resident. This cuts LDS traffic from 0.75 to 0.5 B/flop:
// R11 measured VALUBusy 60% = 91% of the 0.75-B/flop LDS-BW ceiling (66% of
// VALU peak); B-only staging lifts the ceiling to ~VALU peak.
// Proven regressions kept reverted: R3 launch_bounds(256,4) acc spill;
// R6 BK=32 staging spill; R9 LDS dbuf VGPR bloat (keep A-regs to ONE set).
// grid = (ceil(R/64), MB, NC/128)
// AMODE 0: A[b*aBatch + r*K + k]
// AMODE 2: A[(k>>7)*strideM + r*128 + (k&127)]      (gate_in view of [M][N][C])
// AMODE 4: batched gather: row=idx[b*N_+r], Reff=cnts[b], AS[b*N_+row]
// AMODE 5: batched packed:  row=roff[b]+r,  Reff=cnts[b]
// ASCALE 0: none  1: relu(AS[(k>>7)*N_+r]*a)  2: relu(AS[row]*a) (AMODE 4)
// EPI 0: store  1: relu-store
// EPI 5: fused grad-map tail -> recept[b*N_+r]
// EPI 6: relu(acc + bias - sub[r*128+c])            (gm_W1: out1@W1 - xd@W1)
// EPI 7: Cmat[(roff[b]+r)*NC+c] = relu(acc+bias)    (batched packed h)
// EPI 9: Cmat[(roff[b]+r)*128+c] = acc+bias         (batched packed out)
// ---------------------------------------------------------------------------
template<int AMODE, int EPI, int ASCALE>
__global__ void __launch_bounds__(256) gemm12(
    const float* A, const float* A2, const float* __restrict__ B,
    const float* __restrict__ bias, float* Cmat,
    const int* __restrict__ idx, const int* __restrict__ cnts,
    const float* __restrict__ AS, const float* __restrict__ fdbuf,
    const int* __restrict__ roff,
    int R, int K, int NC,
    long long aBatch, long long bBatch, int biasBatch, long long cBatch,
    long long strideM)
{
  __shared__ float Bs[8][128];
  __shared__ float red[(EPI == 5) ? 64 * 17 : 1];

  const int tid = threadIdx.x;
  const int b = blockIdx.y;
  const int Reff = (AMODE == 4 || AMODE == 5) ? cnts[b] : (cnts ? cnts[0] : R);
  const int rb = blockIdx.x * 64;
  if (rb >= Reff) return;
  const int cb = blockIdx.z * 128;

  const float* Ab = (AMODE == 2) ? A : (A + (long long)b * aBatch);
  const float* Bb = B + (long long)b * bBatch + cb;
  const float* biasb = bias + (long long)b * biasBatch + cb;

  // B loader: all 256 threads, 8 k x 128 cols, one float4 each
  const int bk = tid >> 5;
  const int bc = (tid & 31) * 4;

  const int tx = tid & 15;
  const int ty = tid >> 4;            // 0..15
  const int fr = ty * 4;              // fragment base row in tile

  // per-thread fragment row bases (16 tx-threads share addresses -> broadcast)
  bool rv[4]; long long arow[4]; float ars[4];
  #pragma unroll
  for (int i = 0; i < 4; ++i) {
    const int r = rb + fr + i;
    rv[i] = (r < Reff);
    arow[i] = 0; ars[i] = 0.f;
    if (rv[i]) {
      if (AMODE == 4) {
        int orow = idx[(long long)b * N_ + r];
        arow[i] = (long long)orow * K;
        if (ASCALE == 2) ars[i] = AS[(long long)b * N_ + orow];
      } else if (AMODE == 5) {
        arow[i] = (long long)(roff[b] + r) * K;
      } else if (AMODE == 2) {
        arow[i] = (long long)r * 128;
      } else {
        arow[i] = (long long)r * K;
      }
    }
  }

  float acc[4][8];
  #pragma unroll
  for (int i = 0; i < 4; ++i)
    #pragma unroll
    for (int j = 0; j < 8; ++j) acc[i][j] = 0.f;

  const int nt = K >> 3;
  float4 bv;
  float4 af[4];

#define LOADB(k0)                                                              \
  { bv = *(const float4*)(Bb + (long long)((k0) + bk) * NC + bc); }

#define LOADA(k0)                                                              \
  {                                                                            \
    _Pragma("unroll")                                                          \
    for (int i = 0; i < 4; ++i) {                                              \
      if (rv[i]) {                                                             \
        if (AMODE == 2) {                                                      \
          af[i] = *(const float4*)(Ab + (long long)((k0) >> 7) * strideM +     \
                                   arow[i] + ((k0) & 127));                    \
          if (ASCALE == 1) {                                                   \
            float rs = AS[((k0) >> 7) * N_ + (rb + fr + i)];                   \
            af[i].x = fmaxf(af[i].x * rs, 0.f);                                \
            af[i].y = fmaxf(af[i].y * rs, 0.f);                                \
            af[i].z = fmaxf(af[i].z * rs, 0.f);                                \
            af[i].w = fmaxf(af[i].w * rs, 0.f);                                \
          }                                                                    \
        } else {                                                               \
          af[i] = *(const float4*)(Ab + arow[i] + (k0));                       \
          if (AMODE == 4 && ASCALE == 2) {                                     \
            af[i].x = fmaxf(af[i].x * ars[i], 0.f);                            \
            af[i].y = fmaxf(af[i].y * ars[i], 0.f);                            \
            af[i].z = fmaxf(af[i].z * ars[i], 0.f);                            \
            af[i].w = fmaxf(af[i].w * ars[i], 0.f);                            \
          }                                                                    \
        }                                                                      \
      } else {                                                                 \
        af[i] = make_float4(0.f, 0.f, 0.f, 0.f);                               \
      }                                                                        \
    }                                                                          \
  }

#define FMAHALF(base)                                                          \
  {                                                                            \
    _Pragma("unroll")                                                          \
    for (int kk = 0; kk < 4; ++kk) {                                           \
      float4 blo = *(float4*)(&Bs[(base) + kk][tx * 4]);                       \
      float4 bhi = *(float4*)(&Bs[(base) + kk][64 + tx * 4]);                  \
      float b8[8] = {blo.x, blo.y, blo.z, blo.w, bhi.x, bhi.y, bhi.z, bhi.w};  \
      float a_[4] = {((float*)&af[0])[kk], ((float*)&af[1])[kk],               \
                     ((float*)&af[2])[kk], ((float*)&af[3])[kk]};              \
      _Pragma("unroll")                                                        \
      for (int i = 0; i < 4; ++i)                                              \
        _Pragma("unroll")                                                      \
        for (int j = 0; j < 8; ++j)                                            \
          acc[i][j] += a_[i] * b8[j];                                          \
    }                                                                          \
  }

  // stage B tile 0
  LOADB(0)

  for (int t = 0; t < nt; ++t) {
    LOADA(t * 8)       // half 0 — issued before barriers, retires under them
    __syncthreads();   // readers of Bs (tile t-1) done
    *(float4*)(&Bs[bk][bc]) = bv;
    __syncthreads();   // tile t visible
    if (t + 1 < nt) LOADB((t + 1) * 8)   // B prefetch under FMAs

    FMAHALF(0)
    LOADA(t * 8 + 4)   // half 1
    FMAHALF(4)
  }
#undef LOADB
#undef LOADA
#undef FMAHALF

  if (EPI == 5) {
    // fused: mo = sigmoid(acc+bias); gd = mean_c(mo * (out1 - xd)); recept
    #pragma unroll
    for (int i = 0; i < 4; ++i) {
      const int r_local = fr + i;
      const int r = rb + r_local;
      if (r < Reff) {
        const float* fdrow = fdbuf + (long long)b * cBatch + (long long)r * 128;
        const float* xdrow = A2 + (long long)r * 128;
        float4 flo = *(const float4*)(fdrow + tx * 4);
        float4 fhi = *(const float4*)(fdrow + 64 + tx * 4);
        float4 xlo = *(const float4*)(xdrow + tx * 4);
        float4 xhi = *(const float4*)(xdrow + 64 + tx * 4);
        float fd8[8] = {flo.x - xlo.x, flo.y - xlo.y, flo.z - xlo.z, flo.w - xlo.w,
                        fhi.x - xhi.x, fhi.y - xhi.y, fhi.z - xhi.z, fhi.w - xhi.w};
        float p = 0.f;
        #pragma unroll
        for (int j = 0; j < 8; ++j) {
          const int c = (j < 4 ? tx * 4 + j : 64 + tx * 4 + (j - 4));
          float mo = 1.f / (1.f + expf(-(acc[i][j] + biasb[c])));
          p += mo * fd8[j];
        }
        red[r_local * 17 + tx] = p;
      }
    }
    __syncthreads();
    if (tid < 64) {
      const int r = rb + tid;
      if (r < Reff) {
        float s = 0.f;
        #pragma unroll
        for (int t = 0; t < 16; ++t) s += red[tid * 17 + t];
        float gd = s / 128.f;
        Cmat[(long long)b * N_ + r] = gd / (fabsf(gd) + 1e-8f);
      }
    }
    return;
  }

  #pragma unroll
  for (int i = 0; i < 4; ++i) {
    const int r = rb + fr + i;
    if (r >= Reff) continue;
    long long crow;
    if (EPI == 7) crow = (long long)(roff[b] + r) * NC + cb;
    else if (EPI == 9) crow = (long long)(roff[b] + r) * 128 + cb;
    else crow = (long long)b * cBatch + (long long)r * NC + cb;
    const float* subrow = (EPI == 6) ? (fdbuf + (long long)r * 128 + cb) : nullptr;
    #pragma unroll
    for (int j = 0; j < 8; ++j) {
      const int c = (j < 4 ? tx * 4 + j : 64 + tx * 4 + (j - 4));
      float v = acc[i][j] + biasb[c];
      if (EPI == 6) v = fmaxf(v - subrow[c], 0.f);
      if (EPI == 1 || EPI == 7) v = fmaxf(v, 0.f);
      Cmat[crow + c] = v;
    }
  }
}

// a[m*Nn + n] = dot(X[row(n)], lin[m*128 ..]) ; perM: row = m*Nn+n else n
__global__ void attn_logit_kernel(const float* __restrict__ X, const float* __restrict__ lin,
                                  float* __restrict__ out, int Nn, int perM)
{
  int m = blockIdx.y;
  int w = blockIdx.x * (blockDim.x >> 6) + (threadIdx.x >> 6);
  int lane = threadIdx.x & 63;
  if (w >= Nn) return;
  long long row = perM ? ((long long)m * Nn + w) : (long long)w;
  const float* xr = X + row * 128;
  const float* lr = lin + m * 128;
  float acc = xr[lane] * lr[lane] + xr[lane + 64] * lr[lane + 64];
  #pragma unroll
  for (int off = 32; off > 0; off >>= 1) acc += __shfl_down(acc, off);
  if (lane == 0) out[(long long)m * Nn + w] = acc;
}

// ---- CSR build ----
__global__ void count_kernel(const int* __restrict__ dst, int* __restrict__ cnt, int Nn)
{
  int e = blockIdx.x * blockDim.x + threadIdx.x;
  int m = blockIdx.y;
  if (e >= E_) return;
  atomicAdd(&cnt[(long long)m * Nn + dst[(long long)m * E_ + e]], 1);
}

// 3-phase wide scan
__global__ void chunkscan_kernel(const int* __restrict__ cnt, int* __restrict__ rowptr,
                                 int* __restrict__ chunktot)
{
  int m = blockIdx.y, ch = blockIdx.x;
  int base = ch * 1024;
  const int* c = cnt + (long long)m * N_;
  int* rp = rowptr + (long long)m * (N_ + 1);
  __shared__ int sums[256];
  int t = threadIdx.x;
  int v[4]; int s = 0;
  #pragma unroll
  for (int k = 0; k < 4; ++k) {
    int i = base + t * 4 + k;
    v[k] = (i < N_) ? c[i] : 0;
    s += v[k];
  }
  sums[t] = s;
  __syncthreads();
  for (int off = 1; off < 256; off <<= 1) {
    int x = (t >= off) ? sums[t - off] : 0;
    __syncthreads();
    sums[t] += x;
    __syncthreads();
  }
  int run = sums[t] - s;
  #pragma unroll
  for (int k = 0; k < 4; ++k) {
    int i = base + t * 4 + k;
    run += v[k];
    if (i < N_) rp[i + 1] = run;
  }
  if (t == 255) chunktot[m * 64 + ch] = sums[255];
}

__global__ void scantot_kernel(int* __restrict__ chunktot, int nch)
{
  int m = threadIdx.x;
  if (m >= M_) return;
  int run = 0;
  for (int ch = 0; ch < nch; ++ch) {
    int v = chunktot[m * 64 + ch];
    chunktot[m * 64 + ch] = run;
    run += v;
  }
}

__global__ void addoff_kernel(int* __restrict__ rowptr, const int* __restrict__ chunktot)
{
  int m = blockIdx.y, ch = blockIdx.x;
  int off = chunktot[m * 64 + ch];
  int t = threadIdx.x;
  int* rp = rowptr + (long long)m * (N_ + 1);
  #pragma unroll
  for (int k = 0; k < 4; ++k) {
    int i = ch * 1024 + t * 4 + k;
    if (i < N_) rp[i + 1] += off;
  }
  if (ch == 0 && t == 0) rp[0] = 0;
}

__global__ void scatter_kernel(const int* __restrict__ dst, const int* __restrict__ rowptr,
                               int* __restrict__ fill, int* __restrict__ col, int Nn)
{
  int e = blockIdx.x * blockDim.x + threadIdx.x;
  int m = blockIdx.y;
  if (e >= E_) return;
  int d = dst[(long long)m * E_ + e];
  int pos = rowptr[(long long)m * (Nn + 1) + d] + atomicAdd(&fill[(long long)m * Nn + d], 1);
  col[(long long)m * E_ + pos] = e;
}

__global__ void sortbucket_kernel(const int* __restrict__ rowptr, int* __restrict__ col, int Nn)
{
  int n = blockIdx.x * blockDim.x + threadIdx.x;
  int m = blockIdx.y;
  if (n >= Nn) return;
  const int* rp = rowptr + (long long)m * (Nn + 1);
  int* c = col + (long long)m * E_;
  int b = rp[n], e = rp[n + 1];
  for (int i = b + 1; i < e; ++i) {
    int v = c[i]; int j = i - 1;
    while (j >= b && c[j] > v) { c[j + 1] = c[j]; --j; }
    c[j + 1] = v;
  }
}

// per-edge attention logit, edge-parallel
__global__ void edge_e_kernel(const int* __restrict__ src, const int* __restrict__ dst,
                              const float* __restrict__ asrc, const float* __restrict__ adst,
                              float* __restrict__ e_edge)
{
  int e = blockIdx.x * blockDim.x + threadIdx.x;
  int m = blockIdx.y;
  if (e >= E_) return;
  long long off = (long long)m * E_ + e;
  float v = asrc[(long long)m * N_ + src[off]] + adst[(long long)m * N_ + dst[off]];
  e_edge[off] = (v >= 0.f) ? v : 0.2f * v;
}

// per-node softmax over its bucket -> alpha + src id in CSR order
__global__ void alpha_kernel(const int* __restrict__ rowptr, const int* __restrict__ col,
                             const int* __restrict__ src, const float* __restrict__ e_edge,
                             float* __restrict__ alpha, int* __restrict__ src_csr)
{
  int n = blockIdx.x * blockDim.x + threadIdx.x;
  int m = blockIdx.y;
  if (n >= N_) return;
  const int* rp = rowptr + (long long)m * (N_ + 1);
  const int* cl = col + (long long)m * E_;
  const int* sr = src + (long long)m * E_;
  const float* ee = e_edge + (long long)m * E_;
  float* al = alpha + (long long)m * E_;
  int* sc = src_csr + (long long)m * E_;
  int b = rp[n], en = rp[n + 1];
  if (b == en) return;
  float emax = -INFINITY;
  for (int j = b; j < en; ++j) emax = fmaxf(emax, ee[cl[j]]);
  float den = 0.f;
  for (int j = b; j < en; ++j) {
    int eid = cl[j];
    float ez = expf(ee[eid] - emax);
    den += ez;
    al[j] = ez;
    sc[j] = sr[eid];
  }
  float inv = 1.f / (den + 1e-16f);
  for (int j = b; j < en; ++j) al[j] *= inv;
}

// heavy gather: out1[d] = sum_j alpha[j] * xs[src_csr[j]]; 2 dst per block
__global__ void prop2_kernel(const float* __restrict__ xs, const int* __restrict__ rowptr,
                             const float* __restrict__ alpha, const int* __restrict__ src_csr,
                             float* __restrict__ out)
{
  int d = blockIdx.x * 2 + (threadIdx.x >> 7);
  int m = blockIdx.y;
  int c = threadIdx.x & 127;
  if (d >= N_) return;
  const int* rp = rowptr + (long long)m * (N_ + 1);
  const float* al = alpha + (long long)m * E_;
  const int* sc = src_csr + (long long)m * E_;
  const float* xsm = xs + (long long)m * N_ * 128;
  int b = rp[d], en = rp[d + 1];
  float acc = 0.f;
  int j = b;
  for (; j + 3 < en; j += 4) {
    float a0 = al[j], a1 = al[j + 1], a2 = al[j + 2], a3 = al[j + 3];
    int s0 = sc[j], s1 = sc[j + 1], s2 = sc[j + 2], s3 = sc[j + 3];
    float x0 = xsm[(long long)s0 * 128 + c];
    float x1 = xsm[(long long)s1 * 128 + c];
    float x2 = xsm[(long long)s2 * 128 + c];
    float x3 = xsm[(long long)s3 * 128 + c];
    acc += a0 * x0; acc += a1 * x1; acc += a2 * x2; acc += a3 * x3;
  }
  for (; j < en; ++j)
    acc += al[j] * xsm[(long long)sc[j] * 128 + c];
  out[((long long)m * N_ + d) * 128 + c] = acc;
}

// logits[n, 0..3] = h[n,0..255] @ W2[256,4] + b2
__global__ void gate_logits_kernel(const float* __restrict__ h, const float* __restrict__ W2,
                                   const float* __restrict__ b2, float* __restrict__ logits, int Nn)
{
  int w = blockIdx.x * (blockDim.x >> 6) + (threadIdx.x >> 6);
  int lane = threadIdx.x & 63;
  if (w >= Nn) return;
  const float* hr = h + (long long)w * 256;
  float a0 = 0.f, a1 = 0.f, a2 = 0.f, a3 = 0.f;
  for (int j = lane; j < 256; j += 64) {
    float hv = hr[j];
    a0 += hv * W2[j * 4 + 0];
    a1 += hv * W2[j * 4 + 1];
    a2 += hv * W2[j * 4 + 2];
    a3 += hv * W2[j * 4 + 3];
  }
  #pragma unroll
  for (int off = 32; off > 0; off >>= 1) {
    a0 += __shfl_down(a0, off);
    a1 += __shfl_down(a1, off);
    a2 += __shfl_down(a2, off);
    a3 += __shfl_down(a3, off);
  }
  if (lane == 0) {
    long long o = (long long)w * 4;
    logits[o + 0] = a0 + b2[0];
    logits[o + 1] = a1 + b2[1];
    logits[o + 2] = a2 + b2[2];
    logits[o + 3] = a3 + b2[3];
  }
}

// softmax + recept.T + top-2 (ties: lower index) -> wsel[M,N]
__global__ void topk_kernel(const float* __restrict__ logits, const float* __restrict__ recept,
                            float* __restrict__ wsel, int Nn)
{
  int n = blockIdx.x * blockDim.x + threadIdx.x;
  if (n >= Nn) return;
  float l[4];
  #pragma unroll
  for (int m = 0; m < 4; ++m) l[m] = logits[(long long)n * 4 + m];
  float mx = fmaxf(fmaxf(l[0], l[1]), fmaxf(l[2], l[3]));
  float e[4], s = 0.f;
  #pragma unroll
  for (int m = 0; m < 4; ++m) { e[m] = expf(l[m] - mx); s += e[m]; }
  float sc[4];
  #pragma unroll
  for (int m = 0; m < 4; ++m) sc[m] = e[m] / s + recept[(long long)m * Nn + n];
  int i0 = 0; float v0 = sc[0];
  #pragma unroll
  for (int m = 1; m < 4; ++m) if (sc[m] > v0) { v0 = sc[m]; i0 = m; }
  int i1 = -1; float v1 = -INFINITY;
  #pragma unroll
  for (int m = 0; m < 4; ++m) { if (m == i0) continue; if (sc[m] > v1) { v1 = sc[m]; i1 = m; } }
  float ts = v0 + v1;
  float w0 = v0 / ts, w1 = v1 / ts;
  #pragma unroll
  for (int m = 0; m < 4; ++m)
    wsel[(long long)m * Nn + n] = (m == i0) ? w0 : ((m == i1) ? w1 : 0.f);
}

// compaction + record packed position per (m,n)
__global__ void compact_kernel(const float* __restrict__ wsel, int* __restrict__ idx,
                               int* __restrict__ posmn, int* __restrict__ cnts, int Nn)
{
  int n = blockIdx.x * blockDim.x + threadIdx.x;
  if (n >= Nn) return;
  #pragma unroll
  for (int m = 0; m < 4; ++m) {
    if (wsel[(long long)m * Nn + n] != 0.f) {
      int p = atomicAdd(&cnts[m], 1);
      idx[(long long)m * Nn + p] = n;
      posmn[(long long)m * Nn + n] = p;
    }
  }
}

__global__ void prefix4_kernel(const int* __restrict__ cnts, int* __restrict__ off)
{
  if (threadIdx.x == 0) {
    int r = 0;
    #pragma unroll
    for (int m = 0; m < 4; ++m) { off[m] = r; r += cnts[m]; }
  }
}

// final[n] = sum_m wsel[m,n] * outp[(expoff[m]+posmn[m,n])*128 + c]
__global__ void combine_kernel(const float* __restrict__ outp, const float* __restrict__ wsel,
                               const int* __restrict__ posmn, const int* __restrict__ expoff,
                               float* __restrict__ fin)
{
  long long i = (long long)blockIdx.x * blockDim.x + threadIdx.x;
  if (i >= (long long)N_ * 32) return;
  int n = (int)(i >> 5);
  int c4 = (int)(i & 31) * 4;
  float4 acc = make_float4(0.f, 0.f, 0.f, 0.f);
  #pragma unroll
  for (int m = 0; m < 4; ++m) {
    float w = wsel[(long long)m * N_ + n];
    if (w != 0.f) {
      int p = expoff[m] + posmn[(long long)m * N_ + n];
      float4 v = *(const float4*)(outp + (long long)p * 128 + c4);
      acc.x += w * v.x; acc.y += w * v.y; acc.z += w * v.z; acc.w += w * v.w;
    }
  }
  *(float4*)(fin + (long long)n * 128 + c4) = acc;
}

extern "C" void kernel_launch(void* const* d_in, const int* in_sizes, int n_in,
                              void* d_out, int out_size, void* d_ws, size_t ws_size,
                              hipStream_t stream) {
  const float* x_src   = (const float*)d_in[0];
  const float* x_dst   = (const float*)d_in[1];
  const int*   src_idx = (const int*)d_in[2];
  const int*   dst_idx = (const int*)d_in[3];
  const float* proj_Ws = (const float*)d_in[4];
  const float* proj_bs = (const float*)d_in[5];
  const float* projd_W = (const float*)d_in[6];
  const float* projd_b = (const float*)d_in[7];
  const float* lin_src = (const float*)d_in[8];
  const float* lin_dst = (const float*)d_in[9];
  const float* gm_W1   = (const float*)d_in[10];
  const float* gm_b1   = (const float*)d_in[11];
  const float* gm_W2   = (const float*)d_in[12];
  const float* gm_b2   = (const float*)d_in[13];
  const float* gate_W1 = (const float*)d_in[14];
  const float* gate_b1 = (const float*)d_in[15];
  const float* gate_W2 = (const float*)d_in[16];
  const float* gate_b2 = (const float*)d_in[17];
  const float* exp_W1  = (const float*)d_in[18];
  const float* exp_b1  = (const float*)d_in[19];
  const float* exp_W2  = (const float*)d_in[20];
  const float* exp_b2  = (const float*)d_in[21];
  float* final_out = (float*)d_out;

  float* ws = (float*)d_ws;
  float* bufA   = ws;                        // [M,N,128]: xs -> h1 -> gate-h -> packed expert-h
  float* bufB   = ws + 25600000LL;           // [M,N,128]: out1 ; later packed expert-out
  float* xd     = ws + 51200000LL;           // [N,128]
  float* asrc   = ws + 57600000LL;           // [M,N]
  float* adst   = ws + 57800000LL;           // [M,N]
  float* recept = ws + 58000000LL;           // [M,N]
  float* wsel   = ws + 58200000LL;           // [M,N]
  float* logits = ws + 58400000LL;           // [N,4]
  float* e_edge = ws + 58600000LL;           // [M,E]
  float* alpha  = ws + 60200000LL;           // [M,E]
  float* xdW1   = ws + 61800000LL;           // [N,128]
  float* zbuf   = ws + 68200000LL;           // [128] zeros
  int*   ibase  = (int*)(ws + 68300000LL);
  int*   rowptr = ibase;                     // [M,(N+1)]
  int*   col    = ibase + 200004;            // [M,E]
  int*   cnt    = ibase + 1800004;           // [M,N]
  int*   expidx = cnt;                       // reuse after CSR build
  int*   expcnt = ibase + 2000004;           // [4]
  int*   src_csr= ibase + 2000008;           // [M,E]
  int*   chunktot = ibase + 3600008;         // [M,64]
  int*   expoff = ibase + 3600264;           // [4]
  int*   posmn  = ibase + 3600268;           // [M,N]

  const long long NC = (long long)N_ * C_;
  const int RB = (N_ + 63) / 64;             // 782 row blocks (64-row tiles)
  const int NCH = (N_ + 1023) / 1024;        // 49

  // ---- CSR build ----
  hipMemsetAsync(cnt, 0, (size_t)M_ * N_ * sizeof(int), stream);
  hipMemsetAsync(zbuf, 0, 128 * sizeof(float), stream);
  count_kernel<<<dim3((E_ + 255) / 256, M_), 256, 0, stream>>>(dst_idx, cnt, N_);
  chunkscan_kernel<<<dim3(NCH, M_), 256, 0, stream>>>(cnt, rowptr, chunktot);
  scantot_kernel<<<1, 64, 0, stream>>>(chunktot, NCH);
  addoff_kernel<<<dim3(NCH, M_), 256, 0, stream>>>(rowptr, chunktot);
  hipMemsetAsync(cnt, 0, (size_t)M_ * N_ * sizeof(int), stream);
  scatter_kernel<<<dim3((E_ + 255) / 256, M_), 256, 0, stream>>>(dst_idx, rowptr, cnt, col, N_);
  sortbucket_kernel<<<dim3((N_ + 255) / 256, M_), 256, 0, stream>>>(rowptr, col, N_);

  // ---- xd = x_dst @ projd_W + b ----
  gemm12<0, 0, 0><<<dim3(RB, 1, 1), 256, 0, stream>>>(
      x_dst, nullptr, projd_W, projd_b, xd, nullptr, nullptr, nullptr, nullptr,
      nullptr, N_, IN_, C_, 0, 0, 0, 0, 0);
  attn_logit_kernel<<<dim3((N_ + 3) / 4, M_), 256, 0, stream>>>(xd, lin_dst, adst, N_, 0);

  // ---- xdW1 = xd @ gm_W1 (zero bias; used by gm_W1 epilogue subtract) ----
  gemm12<0, 0, 0><<<dim3(RB, 1, 1), 256, 0, stream>>>(
      xd, nullptr, gm_W1, zbuf, xdW1, nullptr, nullptr, nullptr, nullptr,
      nullptr, N_, C_, C_, 0, 0, 0, 0, 0);

  // ---- xs = per-type projection (batched over m) ----
  gemm12<0, 0, 0><<<dim3(RB, M_, 1), 256, 0, stream>>>(
      x_src, nullptr, proj_Ws, proj_bs, bufA, nullptr, nullptr, nullptr, nullptr,
      nullptr, N_, IN_, C_, NC, (long long)IN_ * C_, C_, NC, 0);
  attn_logit_kernel<<<dim3((N_ + 3) / 4, M_), 256, 0, stream>>>(bufA, lin_src, asrc, N_, 1);

  // ---- attention softmax precompute ----
  edge_e_kernel<<<dim3((E_ + 255) / 256, M_), 256, 0, stream>>>(
      src_idx, dst_idx, asrc, adst, e_edge);
  alpha_kernel<<<dim3((N_ + 255) / 256, M_), 256, 0, stream>>>(
      rowptr, col, src_idx, e_edge, alpha, src_csr);

  // ---- propagation (single gather pass) -> out1 in bufB ----
  prop2_kernel<<<dim3((N_ + 1) / 2, M_), 256, 0, stream>>>(bufA, rowptr, alpha, src_csr, bufB);

  // ---- grad-map MLP: h1 = relu(out1@W1 + b1 - xdW1); fused W2 tail -> recept ----
  gemm12<0, 6, 0><<<dim3(RB, M_, 1), 256, 0, stream>>>(
      bufB, nullptr, gm_W1, gm_b1, bufA, nullptr, nullptr, nullptr, xdW1,
      nullptr, N_, C_, C_, NC, 0, 0, NC, 0);
  gemm12<0, 5, 0><<<dim3(RB, M_, 1), 256, 0, stream>>>(
      bufA, xd, gm_W2, gm_b2, recept, nullptr, nullptr, nullptr, bufB,
      nullptr, N_, C_, C_, NC, 0, 0, NC, 0);

  // ---- gate: h = relu(gate_in @ W1 + b1); feats fused on A-load ----
  gemm12<2, 1, 1><<<dim3(RB, 1, 2), 256, 0, stream>>>(
      bufB, nullptr, gate_W1, gate_b1, bufA, nullptr, nullptr, recept, nullptr,
      nullptr, N_, M_ * C_, HID_, 0, 0, 0, 0, NC);
  gate_logits_kernel<<<dim3((N_ + 3) / 4), 256, 0, stream>>>(bufA, gate_W2, gate_b2, logits, N_);
  topk_kernel<<<(N_ + 255) / 256, 256, 0, stream>>>(logits, recept, wsel, N_);

  // ---- top-2 compaction + packed row offsets ----
  hipMemsetAsync(expcnt, 0, 4 * sizeof(int), stream);
  compact_kernel<<<(N_ + 255) / 256, 256, 0, stream>>>(wsel, expidx, posmn, expcnt, N_);
  prefix4_kernel<<<1, 64, 0, stream>>>(expcnt, expoff);

  // ---- experts: batched W1 (packed h in bufA), batched W2 (packed out), combine ----
  gemm12<4, 7, 2><<<dim3(RB, M_, 2), 256, 0, stream>>>(
      bufB, nullptr, exp_W1, exp_b1, bufA, expidx, expcnt, recept, nullptr,
      expoff, N_, C_, HID_, NC, (long long)C_ * HID_, HID_, 0, 0);
  gemm12<5, 9, 0><<<dim3(RB, M_, 1), 256, 0, stream>>>(
      bufA, nullptr, exp_W2, exp_b2, bufB, expidx, expcnt, nullptr, nullptr,
      expoff, N_, HID_, C_, 0, (long long)HID_ * C_, C_, 0, 0);
  combine_kernel<<<(int)(((long long)N_ * 32 + 255) / 256), 256, 0, stream>>>(
      bufB, wsel, posmn, expoff, final_out);
}

// Round 13
// 1308.115 us; speedup vs baseline: 1.5084x; 1.5084x over previous
//
#include <hip/hip_runtime.h>
#include <hip/hip_bf16.h>
#include <math.h>

#define M_  4
#define N_  50000
#define E_  400000
#define IN_ 128
#define C_  128
#define HID_ 256

// ---------------------------------------------------------------------------
// Tiled f32 GEMM: 96 rows x 128 cols, 256 threads, 6x8 micro, BK=8,
// single LDS buffer, 2 barriers/tile, 8-VGPR register prefetch.
// WHY 6x8: micro-tile LDS traffic = 2(m+n)/(m*n) B/flop. 8x8 = 0.50 B/flop
// but grid-limits the gate to 12.2 waves/CU (53% VALU, latency-bound);
// 4x8 = 0.75 B/flop -> LDS-BW ceiling 66% of peak (R11 measured 60% = 91%
// of ceiling). 6x8 = 0.583 B/flop (ceiling 86%) at 16.3 waves/CU.
// Proven regressions kept reverted: R3 launch_bounds(256,4) acc spill;
// R6 BK=32 staging spill; R9 LDS dbuf VGPR bloat; R12 A-direct-from-global
// (dependent per-tile VMEM loads, no latency hiding, 2.2x slower).
// grid = (ceil(R/96), MB, NC/128)
// AMODE 0: A[b*aBatch + r*K + k]
// AMODE 2: A[(k>>7)*strideM + r*128 + (k&127)]      (gate_in view of [M][N][C])
// AMODE 4: batched gather: row=idx[b*N_+r], Reff=cnts[b], AS[b*N_+row]
// AMODE 5: batched packed:  row=roff[b]+r,  Reff=cnts[b]
// ASCALE 0: none  1: relu(AS[(k>>7)*N_+r]*a)  2: relu(AS[row]*a) (AMODE 4)
// EPI 0: store  1: relu-store
// EPI 5: fused grad-map tail -> recept[b*N_+r]
// EPI 6: relu(acc + bias - sub[r*128+c])            (gm_W1: out1@W1 - xd@W1)
// EPI 7: Cmat[(roff[b]+r)*NC+c] = relu(acc+bias)    (batched packed h)
// EPI 9: Cmat[(roff[b]+r)*128+c] = acc+bias         (batched packed out)
// ---------------------------------------------------------------------------
template<int AMODE, int EPI, int ASCALE>
__global__ void __launch_bounds__(256) gemm13(
    const float* A, const float* A2, const float* __restrict__ B,
    const float* __restrict__ bias, float* Cmat,
    const int* __restrict__ idx, const int* __restrict__ cnts,
    const float* __restrict__ AS, const float* __restrict__ fdbuf,
    const int* __restrict__ roff,
    int R, int K, int NC,
    long long aBatch, long long bBatch, int biasBatch, long long cBatch,
    long long strideM)
{
  __shared__ float As[8][96];
  __shared__ float Bs[8][128];
  __shared__ float red[(EPI == 5) ? 96 * 17 : 1];

  const int tid = threadIdx.x;
  const int b = blockIdx.y;
  const int Reff = (AMODE == 4 || AMODE == 5) ? cnts[b] : (cnts ? cnts[0] : R);
  const int rb = blockIdx.x * 96;
  if (rb >= Reff) return;
  const int cb = blockIdx.z * 128;

  const float* Ab = (AMODE == 2) ? A : (A + (long long)b * aBatch);
  const float* Bb = B + (long long)b * bBatch + cb;
  const float* biasb = bias + (long long)b * biasBatch + cb;

  // A loader: first 192 threads, 96 rows x 8 k, one float4 each
  const int ar = tid >> 1;            // 0..95 (tid<192)
  const int ak = (tid & 1) * 4;       // 0 or 4
  const int r_a = rb + ar;
  const bool a_ok = (tid < 192) && (r_a < Reff);
  long long a_row = 0;
  float a_rs = 0.f;
  if (a_ok) {
    if (AMODE == 4) {
      int orow = idx[(long long)b * N_ + r_a];
      a_row = (long long)orow * K;
      if (ASCALE == 2) a_rs = AS[(long long)b * N_ + orow];
    } else if (AMODE == 5) {
      a_row = (long long)(roff[b] + r_a) * K;
    } else if (AMODE == 2) {
      a_row = (long long)r_a * 128;
    } else {
      a_row = (long long)r_a * K;
    }
  }
  // B loader: all 256 threads, 8 k x 128 cols, one float4 each
  const int bk = tid >> 5;
  const int bc = (tid & 31) * 4;

  const int tx = tid & 15;
  const int ty = tid >> 4;            // 0..15
  const int fr = ty * 6;              // fragment base row in tile (0..90)

  float acc[6][8];
  #pragma unroll
  for (int i = 0; i < 6; ++i)
    #pragma unroll
    for (int j = 0; j < 8; ++j) acc[i][j] = 0.f;

  const int nt = K >> 3;
  float4 av = make_float4(0.f, 0.f, 0.f, 0.f), bv;

#define LOAD_TILE(k0)                                                          \
  {                                                                            \
    if (a_ok) {                                                                \
      if (AMODE == 2) {                                                        \
        int kk0 = (k0) + ak;                                                   \
        av = *(const float4*)(Ab + (long long)(kk0 >> 7) * strideM + a_row +   \
                              (kk0 & 127));                                    \
        if (ASCALE == 1) {                                                     \
          float rs = AS[(kk0 >> 7) * N_ + r_a];                                \
          av.x = fmaxf(av.x * rs, 0.f); av.y = fmaxf(av.y * rs, 0.f);          \
          av.z = fmaxf(av.z * rs, 0.f); av.w = fmaxf(av.w * rs, 0.f);          \
        }                                                                      \
      } else {                                                                 \
        av = *(const float4*)(Ab + a_row + (k0) + ak);                         \
        if (AMODE == 4 && ASCALE == 2) {                                       \
          av.x = fmaxf(av.x * a_rs, 0.f); av.y = fmaxf(av.y * a_rs, 0.f);      \
          av.z = fmaxf(av.z * a_rs, 0.f); av.w = fmaxf(av.w * a_rs, 0.f);      \
        }                                                                      \
      }                                                                        \
    } else {                                                                   \
      av = make_float4(0.f, 0.f, 0.f, 0.f);                                    \
    }                                                                          \
    bv = *(const float4*)(Bb + (long long)((k0) + bk) * NC + bc);              \
  }

  // stage tile 0
  LOAD_TILE(0)

  for (int t = 0; t < nt; ++t) {
    __syncthreads();   // readers of LDS (tile t-1) done
    if (tid < 192) {
      As[ak + 0][ar] = av.x; As[ak + 1][ar] = av.y;
      As[ak + 2][ar] = av.z; As[ak + 3][ar] = av.w;
    }
    *(float4*)(&Bs[bk][bc]) = bv;
    __syncthreads();   // tile t visible

    // prefetch tile t+1: loads retire under the FMA block below
    if (t + 1 < nt) LOAD_TILE((t + 1) * 8)

    #pragma unroll
    for (int kk = 0; kk < 8; ++kk) {
      float2 a01 = *(float2*)(&As[kk][fr]);
      float2 a23 = *(float2*)(&As[kk][fr + 2]);
      float2 a45 = *(float2*)(&As[kk][fr + 4]);
      float4 blo = *(float4*)(&Bs[kk][tx * 4]);
      float4 bhi = *(float4*)(&Bs[kk][64 + tx * 4]);
      float a_[6] = {a01.x, a01.y, a23.x, a23.y, a45.x, a45.y};
      float b8[8] = {blo.x, blo.y, blo.z, blo.w, bhi.x, bhi.y, bhi.z, bhi.w};
      #pragma unroll
      for (int i = 0; i < 6; ++i)
        #pragma unroll
        for (int j = 0; j < 8; ++j)
          acc[i][j] += a_[i] * b8[j];
    }
  }
#undef LOAD_TILE

  if (EPI == 5) {
    // fused: mo = sigmoid(acc+bias); gd = mean_c(mo * (out1 - xd)); recept
    #pragma unroll
    for (int i = 0; i < 6; ++i) {
      const int r_local = fr + i;
      const int r = rb + r_local;
      if (r < Reff) {
        const float* fdrow = fdbuf + (long long)b * cBatch + (long long)r * 128;
        const float* xdrow = A2 + (long long)r * 128;
        float4 flo = *(const float4*)(fdrow + tx * 4);
        float4 fhi = *(const float4*)(fdrow + 64 + tx * 4);
        float4 xlo = *(const float4*)(xdrow + tx * 4);
        float4 xhi = *(const float4*)(xdrow + 64 + tx * 4);
        float fd8[8] = {flo.x - xlo.x, flo.y - xlo.y, flo.z - xlo.z, flo.w - xlo.w,
                        fhi.x - xhi.x, fhi.y - xhi.y, fhi.z - xhi.z, fhi.w - xhi.w};
        float p = 0.f;
        #pragma unroll
        for (int j = 0; j < 8; ++j) {
          const int c = (j < 4 ? tx * 4 + j : 64 + tx * 4 + (j - 4));
          float mo = 1.f / (1.f + expf(-(acc[i][j] + biasb[c])));
          p += mo * fd8[j];
        }
        red[r_local * 17 + tx] = p;
      }
    }
    __syncthreads();
    if (tid < 96) {
      const int r = rb + tid;
      if (r < Reff) {
        float s = 0.f;
        #pragma unroll
        for (int t = 0; t < 16; ++t) s += red[tid * 17 + t];
        float gd = s / 128.f;
        Cmat[(long long)b * N_ + r] = gd / (fabsf(gd) + 1e-8f);
      }
    }
    return;
  }

  #pragma unroll
  for (int i = 0; i < 6; ++i) {
    const int r = rb + fr + i;
    if (r >= Reff) continue;
    long long crow;
    if (EPI == 7) crow = (long long)(roff[b] + r) * NC + cb;
    else if (EPI == 9) crow = (long long)(roff[b] + r) * 128 + cb;
    else crow = (long long)b * cBatch + (long long)r * NC + cb;
    const float* subrow = (EPI == 6) ? (fdbuf + (long long)r * 128 + cb) : nullptr;
    #pragma unroll
    for (int j = 0; j < 8; ++j) {
      const int c = (j < 4 ? tx * 4 + j : 64 + tx * 4 + (j - 4));
      float v = acc[i][j] + biasb[c];
      if (EPI == 6) v = fmaxf(v - subrow[c], 0.f);
      if (EPI == 1 || EPI == 7) v = fmaxf(v, 0.f);
      Cmat[crow + c] = v;
    }
  }
}

// a[m*Nn + n] = dot(X[row(n)], lin[m*128 ..]) ; perM: row = m*Nn+n else n
__global__ void attn_logit_kernel(const float* __restrict__ X, const float* __restrict__ lin,
                                  float* __restrict__ out, int Nn, int perM)
{
  int m = blockIdx.y;
  int w = blockIdx.x * (blockDim.x >> 6) + (threadIdx.x >> 6);
  int lane = threadIdx.x & 63;
  if (w >= Nn) return;
  long long row = perM ? ((long long)m * Nn + w) : (long long)w;
  const float* xr = X + row * 128;
  const float* lr = lin + m * 128;
  float acc = xr[lane] * lr[lane] + xr[lane + 64] * lr[lane + 64];
  #pragma unroll
  for (int off = 32; off > 0; off >>= 1) acc += __shfl_down(acc, off);
  if (lane == 0) out[(long long)m * Nn + w] = acc;
}

// ---- CSR build ----
__global__ void count_kernel(const int* __restrict__ dst, int* __restrict__ cnt, int Nn)
{
  int e = blockIdx.x * blockDim.x + threadIdx.x;
  int m = blockIdx.y;
  if (e >= E_) return;
  atomicAdd(&cnt[(long long)m * Nn + dst[(long long)m * E_ + e]], 1);
}

// 3-phase wide scan
__global__ void chunkscan_kernel(const int* __restrict__ cnt, int* __restrict__ rowptr,
                                 int* __restrict__ chunktot)
{
  int m = blockIdx.y, ch = blockIdx.x;
  int base = ch * 1024;
  const int* c = cnt + (long long)m * N_;
  int* rp = rowptr + (long long)m * (N_ + 1);
  __shared__ int sums[256];
  int t = threadIdx.x;
  int v[4]; int s = 0;
  #pragma unroll
  for (int k = 0; k < 4; ++k) {
    int i = base + t * 4 + k;
    v[k] = (i < N_) ? c[i] : 0;
    s += v[k];
  }
  sums[t] = s;
  __syncthreads();
  for (int off = 1; off < 256; off <<= 1) {
    int x = (t >= off) ? sums[t - off] : 0;
    __syncthreads();
    sums[t] += x;
    __syncthreads();
  }
  int run = sums[t] - s;
  #pragma unroll
  for (int k = 0; k < 4; ++k) {
    int i = base + t * 4 + k;
    run += v[k];
    if (i < N_) rp[i + 1] = run;
  }
  if (t == 255) chunktot[m * 64 + ch] = sums[255];
}

__global__ void scantot_kernel(int* __restrict__ chunktot, int nch)
{
  int m = threadIdx.x;
  if (m >= M_) return;
  int run = 0;
  for (int ch = 0; ch < nch; ++ch) {
    int v = chunktot[m * 64 + ch];
    chunktot[m * 64 + ch] = run;
    run += v;
  }
}

__global__ void addoff_kernel(int* __restrict__ rowptr, const int* __restrict__ chunktot)
{
  int m = blockIdx.y, ch = blockIdx.x;
  int off = chunktot[m * 64 + ch];
  int t = threadIdx.x;
  int* rp = rowptr + (long long)m * (N_ + 1);
  #pragma unroll
  for (int k = 0; k < 4; ++k) {
    int i = ch * 1024 + t * 4 + k;
    if (i < N_) rp[i + 1] += off;
  }
  if (ch == 0 && t == 0) rp[0] = 0;
}

__global__ void scatter_kernel(const int* __restrict__ dst, const int* __restrict__ rowptr,
                               int* __restrict__ fill, int* __restrict__ col, int Nn)
{
  int e = blockIdx.x * blockDim.x + threadIdx.x;
  int m = blockIdx.y;
  if (e >= E_) return;
  int d = dst[(long long)m * E_ + e];
  int pos = rowptr[(long long)m * (Nn + 1) + d] + atomicAdd(&fill[(long long)m * Nn + d], 1);
  col[(long long)m * E_ + pos] = e;
}

__global__ void sortbucket_kernel(const int* __restrict__ rowptr, int* __restrict__ col, int Nn)
{
  int n = blockIdx.x * blockDim.x + threadIdx.x;
  int m = blockIdx.y;
  if (n >= Nn) return;
  const int* rp = rowptr + (long long)m * (Nn + 1);
  int* c = col + (long long)m * E_;
  int b = rp[n], e = rp[n + 1];
  for (int i = b + 1; i < e; ++i) {
    int v = c[i]; int j = i - 1;
    while (j >= b && c[j] > v) { c[j + 1] = c[j]; --j; }
    c[j + 1] = v;
  }
}

// per-edge attention logit, edge-parallel
__global__ void edge_e_kernel(const int* __restrict__ src, const int* __restrict__ dst,
                              const float* __restrict__ asrc, const float* __restrict__ adst,
                              float* __restrict__ e_edge)
{
  int e = blockIdx.x * blockDim.x + threadIdx.x;
  int m = blockIdx.y;
  if (e >= E_) return;
  long long off = (long long)m * E_ + e;
  float v = asrc[(long long)m * N_ + src[off]] + adst[(long long)m * N_ + dst[off]];
  e_edge[off] = (v >= 0.f) ? v : 0.2f * v;
}

// per-node softmax over its bucket -> alpha + src id in CSR order
__global__ void alpha_kernel(const int* __restrict__ rowptr, const int* __restrict__ col,
                             const int* __restrict__ src, const float* __restrict__ e_edge,
                             float* __restrict__ alpha, int* __restrict__ src_csr)
{
  int n = blockIdx.x * blockDim.x + threadIdx.x;
  int m = blockIdx.y;
  if (n >= N_) return;
  const int* rp = rowptr + (long long)m * (N_ + 1);
  const int* cl = col + (long long)m * E_;
  const int* sr = src + (long long)m * E_;
  const float* ee = e_edge + (long long)m * E_;
  float* al = alpha + (long long)m * E_;
  int* sc = src_csr + (long long)m * E_;
  int b = rp[n], en = rp[n + 1];
  if (b == en) return;
  float emax = -INFINITY;
  for (int j = b; j < en; ++j) emax = fmaxf(emax, ee[cl[j]]);
  float den = 0.f;
  for (int j = b; j < en; ++j) {
    int eid = cl[j];
    float ez = expf(ee[eid] - emax);
    den += ez;
    al[j] = ez;
    sc[j] = sr[eid];
  }
  float inv = 1.f / (den + 1e-16f);
  for (int j = b; j < en; ++j) al[j] *= inv;
}

// heavy gather: out1[d] = sum_j alpha[j] * xs[src_csr[j]]; 2 dst per block
__global__ void prop2_kernel(const float* __restrict__ xs, const int* __restrict__ rowptr,
                             const float* __restrict__ alpha, const int* __restrict__ src_csr,
                             float* __restrict__ out)
{
  int d = blockIdx.x * 2 + (threadIdx.x >> 7);
  int m = blockIdx.y;
  int c = threadIdx.x & 127;
  if (d >= N_) return;
  const int* rp = rowptr + (long long)m * (N_ + 1);
  const float* al = alpha + (long long)m * E_;
  const int* sc = src_csr + (long long)m * E_;
  const float* xsm = xs + (long long)m * N_ * 128;
  int b = rp[d], en = rp[d + 1];
  float acc = 0.f;
  int j = b;
  for (; j + 3 < en; j += 4) {
    float a0 = al[j], a1 = al[j + 1], a2 = al[j + 2], a3 = al[j + 3];
    int s0 = sc[j], s1 = sc[j + 1], s2 = sc[j + 2], s3 = sc[j + 3];
    float x0 = xsm[(long long)s0 * 128 + c];
    float x1 = xsm[(long long)s1 * 128 + c];
    float x2 = xsm[(long long)s2 * 128 + c];
    float x3 = xsm[(long long)s3 * 128 + c];
    acc += a0 * x0; acc += a1 * x1; acc += a2 * x2; acc += a3 * x3;
  }
  for (; j < en; ++j)
    acc += al[j] * xsm[(long long)sc[j] * 128 + c];
  out[((long long)m * N_ + d) * 128 + c] = acc;
}

// logits[n, 0..3] = h[n,0..255] @ W2[256,4] + b2
__global__ void gate_logits_kernel(const float* __restrict__ h, const float* __restrict__ W2,
                                   const float* __restrict__ b2, float* __restrict__ logits, int Nn)
{
  int w = blockIdx.x * (blockDim.x >> 6) + (threadIdx.x >> 6);
  int lane = threadIdx.x & 63;
  if (w >= Nn) return;
  const float* hr = h + (long long)w * 256;
  float a0 = 0.f, a1 = 0.f, a2 = 0.f, a3 = 0.f;
  for (int j = lane; j < 256; j += 64) {
    float hv = hr[j];
    a0 += hv * W2[j * 4 + 0];
    a1 += hv * W2[j * 4 + 1];
    a2 += hv * W2[j * 4 + 2];
    a3 += hv * W2[j * 4 + 3];
  }
  #pragma unroll
  for (int off = 32; off > 0; off >>= 1) {
    a0 += __shfl_down(a0, off);
    a1 += __shfl_down(a1, off);
    a2 += __shfl_down(a2, off);
    a3 += __shfl_down(a3, off);
  }
  if (lane == 0) {
    long long o = (long long)w * 4;
    logits[o + 0] = a0 + b2[0];
    logits[o + 1] = a1 + b2[1];
    logits[o + 2] = a2 + b2[2];
    logits[o + 3] = a3 + b2[3];
  }
}

// softmax + recept.T + top-2 (ties: lower index) -> wsel[M,N]
__global__ void topk_kernel(const float* __restrict__ logits, const float* __restrict__ recept,
                            float* __restrict__ wsel, int Nn)
{
  int n = blockIdx.x * blockDim.x + threadIdx.x;
  if (n >= Nn) return;
  float l[4];
  #pragma unroll
  for (int m = 0; m < 4; ++m) l[m] = logits[(long long)n * 4 + m];
  float mx = fmaxf(fmaxf(l[0], l[1]), fmaxf(l[2], l[3]));
  float e[4], s = 0.f;
  #pragma unroll
  for (int m = 0; m < 4; ++m) { e[m] = expf(l[m] - mx); s += e[m]; }
  float sc[4];
  #pragma unroll
  for (int m = 0; m < 4; ++m) sc[m] = e[m] / s + recept[(long long)m * Nn + n];
  int i0 = 0; float v0 = sc[0];
  #pragma unroll
  for (int m = 1; m < 4; ++m) if (sc[m] > v0) { v0 = sc[m]; i0 = m; }
  int i1 = -1; float v1 = -INFINITY;
  #pragma unroll
  for (int m = 0; m < 4; ++m) { if (m == i0) continue; if (sc[m] > v1) { v1 = sc[m]; i1 = m; } }
  float ts = v0 + v1;
  float w0 = v0 / ts, w1 = v1 / ts;
  #pragma unroll
  for (int m = 0; m < 4; ++m)
    wsel[(long long)m * Nn + n] = (m == i0) ? w0 : ((m == i1) ? w1 : 0.f);
}

// compaction + record packed position per (m,n)
__global__ void compact_kernel(const float* __restrict__ wsel, int* __restrict__ idx,
                               int* __restrict__ posmn, int* __restrict__ cnts, int Nn)
{
  int n = blockIdx.x * blockDim.x + threadIdx.x;
  if (n >= Nn) return;
  #pragma unroll
  for (int m = 0; m < 4; ++m) {
    if (wsel[(long long)m * Nn + n] != 0.f) {
      int p = atomicAdd(&cnts[m], 1);
      idx[(long long)m * Nn + p] = n;
      posmn[(long long)m * Nn + n] = p;
    }
  }
}

__global__ void prefix4_kernel(const int* __restrict__ cnts, int* __restrict__ off)
{
  if (threadIdx.x == 0) {
    int r = 0;
    #pragma unroll
    for (int m = 0; m < 4; ++m) { off[m] = r; r += cnts[m]; }
  }
}

// final[n] = sum_m wsel[m,n] * outp[(expoff[m]+posmn[m,n])*128 + c]
__global__ void combine_kernel(const float* __restrict__ outp, const float* __restrict__ wsel,
                               const int* __restrict__ posmn, const int* __restrict__ expoff,
                               float* __restrict__ fin)
{
  long long i = (long long)blockIdx.x * blockDim.x + threadIdx.x;
  if (i >= (long long)N_ * 32) return;
  int n = (int)(i >> 5);
  int c4 = (int)(i & 31) * 4;
  float4 acc = make_float4(0.f, 0.f, 0.f, 0.f);
  #pragma unroll
  for (int m = 0; m < 4; ++m) {
    float w = wsel[(long long)m * N_ + n];
    if (w != 0.f) {
      int p = expoff[m] + posmn[(long long)m * N_ + n];
      float4 v = *(const float4*)(outp + (long long)p * 128 + c4);
      acc.x += w * v.x; acc.y += w * v.y; acc.z += w * v.z; acc.w += w * v.w;
    }
  }
  *(float4*)(fin + (long long)n * 128 + c4) = acc;
}

extern "C" void kernel_launch(void* const* d_in, const int* in_sizes, int n_in,
                              void* d_out, int out_size, void* d_ws, size_t ws_size,
                              hipStream_t stream) {
  const float* x_src   = (const float*)d_in[0];
  const float* x_dst   = (const float*)d_in[1];
  const int*   src_idx = (const int*)d_in[2];
  const int*   dst_idx = (const int*)d_in[3];
  const float* proj_Ws = (const float*)d_in[4];
  const float* proj_bs = (const float*)d_in[5];
  const float* projd_W = (const float*)d_in[6];
  const float* projd_b = (const float*)d_in[7];
  const float* lin_src = (const float*)d_in[8];
  const float* lin_dst = (const float*)d_in[9];
  const float* gm_W1   = (const float*)d_in[10];
  const float* gm_b1   = (const float*)d_in[11];
  const float* gm_W2   = (const float*)d_in[12];
  const float* gm_b2   = (const float*)d_in[13];
  const float* gate_W1 = (const float*)d_in[14];
  const float* gate_b1 = (const float*)d_in[15];
  const float* gate_W2 = (const float*)d_in[16];
  const float* gate_b2 = (const float*)d_in[17];
  const float* exp_W1  = (const float*)d_in[18];
  const float* exp_b1  = (const float*)d_in[19];
  const float* exp_W2  = (const float*)d_in[20];
  const float* exp_b2  = (const float*)d_in[21];
  float* final_out = (float*)d_out;

  float* ws = (float*)d_ws;
  float* bufA   = ws;                        // [M,N,128]: xs -> h1 -> gate-h -> packed expert-h
  float* bufB   = ws + 25600000LL;           // [M,N,128]: out1 ; later packed expert-out
  float* xd     = ws + 51200000LL;           // [N,128]
  float* asrc   = ws + 57600000LL;           // [M,N]
  float* adst   = ws + 57800000LL;           // [M,N]
  float* recept = ws + 58000000LL;           // [M,N]
  float* wsel   = ws + 58200000LL;           // [M,N]
  float* logits = ws + 58400000LL;           // [N,4]
  float* e_edge = ws + 58600000LL;           // [M,E]
  float* alpha  = ws + 60200000LL;           // [M,E]
  float* xdW1   = ws + 61800000LL;           // [N,128]
  float* zbuf   = ws + 68200000LL;           // [128] zeros
  int*   ibase  = (int*)(ws + 68300000LL);
  int*   rowptr = ibase;                     // [M,(N+1)]
  int*   col    = ibase + 200004;            // [M,E]
  int*   cnt    = ibase + 1800004;           // [M,N]
  int*   expidx = cnt;                       // reuse after CSR build
  int*   expcnt = ibase + 2000004;           // [4]
  int*   src_csr= ibase + 2000008;           // [M,E]
  int*   chunktot = ibase + 3600008;         // [M,64]
  int*   expoff = ibase + 3600264;           // [4]
  int*   posmn  = ibase + 3600268;           // [M,N]

  const long long NC = (long long)N_ * C_;
  const int RB = (N_ + 95) / 96;             // 521 row blocks (96-row tiles)
  const int NCH = (N_ + 1023) / 1024;        // 49

  // ---- CSR build ----
  hipMemsetAsync(cnt, 0, (size_t)M_ * N_ * sizeof(int), stream);
  hipMemsetAsync(zbuf, 0, 128 * sizeof(float), stream);
  count_kernel<<<dim3((E_ + 255) / 256, M_), 256, 0, stream>>>(dst_idx, cnt, N_);
  chunkscan_kernel<<<dim3(NCH, M_), 256, 0, stream>>>(cnt, rowptr, chunktot);
  scantot_kernel<<<1, 64, 0, stream>>>(chunktot, NCH);
  addoff_kernel<<<dim3(NCH, M_), 256, 0, stream>>>(rowptr, chunktot);
  hipMemsetAsync(cnt, 0, (size_t)M_ * N_ * sizeof(int), stream);
  scatter_kernel<<<dim3((E_ + 255) / 256, M_), 256, 0, stream>>>(dst_idx, rowptr, cnt, col, N_);
  sortbucket_kernel<<<dim3((N_ + 255) / 256, M_), 256, 0, stream>>>(rowptr, col, N_);

  // ---- xd = x_dst @ projd_W + b ----
  gemm13<0, 0, 0><<<dim3(RB, 1, 1), 256, 0, stream>>>(
      x_dst, nullptr, projd_W, projd_b, xd, nullptr, nullptr, nullptr, nullptr,
      nullptr, N_, IN_, C_, 0, 0, 0, 0, 0);
  attn_logit_kernel<<<dim3((N_ + 3) / 4, M_), 256, 0, stream>>>(xd, lin_dst, adst, N_, 0);

  // ---- xdW1 = xd @ gm_W1 (zero bias; used by gm_W1 epilogue subtract) ----
  gemm13<0, 0, 0><<<dim3(RB, 1, 1), 256, 0, stream>>>(
      xd, nullptr, gm_W1, zbuf, xdW1, nullptr, nullptr, nullptr, nullptr,
      nullptr, N_, C_, C_, 0, 0, 0, 0, 0);

  // ---- xs = per-type projection (batched over m) ----
  gemm13<0, 0, 0><<<dim3(RB, M_, 1), 256, 0, stream>>>(
      x_src, nullptr, proj_Ws, proj_bs, bufA, nullptr, nullptr, nullptr, nullptr,
      nullptr, N_, IN_, C_, NC, (long long)IN_ * C_, C_, NC, 0);
  attn_logit_kernel<<<dim3((N_ + 3) / 4, M_), 256, 0, stream>>>(bufA, lin_src, asrc, N_, 1);

  // ---- attention softmax precompute ----
  edge_e_kernel<<<dim3((E_ + 255) / 256, M_), 256, 0, stream>>>(
      src_idx, dst_idx, asrc, adst, e_edge);
  alpha_kernel<<<dim3((N_ + 255) / 256, M_), 256, 0, stream>>>(
      rowptr, col, src_idx, e_edge, alpha, src_csr);

  // ---- propagation (single gather pass) -> out1 in bufB ----
  prop2_kernel<<<dim3((N_ + 1) / 2, M_), 256, 0, stream>>>(bufA, rowptr, alpha, src_csr, bufB);

  // ---- grad-map MLP: h1 = relu(out1@W1 + b1 - xdW1); fused W2 tail -> recept ----
  gemm13<0, 6, 0><<<dim3(RB, M_, 1), 256, 0, stream>>>(
      bufB, nullptr, gm_W1, gm_b1, bufA, nullptr, nullptr, nullptr, xdW1,
      nullptr, N_, C_, C_, NC, 0, 0, NC, 0);
  gemm13<0, 5, 0><<<dim3(RB, M_, 1), 256, 0, stream>>>(
      bufA, xd, gm_W2, gm_b2, recept, nullptr, nullptr, nullptr, bufB,
      nullptr, N_, C_, C_, NC, 0, 0, NC, 0);

  // ---- gate: h = relu(gate_in @ W1 + b1); feats fused on A-load ----
  gemm13<2, 1, 1><<<dim3(RB, 1, 2), 256, 0, stream>>>(
      bufB, nullptr, gate_W1, gate_b1, bufA, nullptr, nullptr, recept, nullptr,
      nullptr, N_, M_ * C_, HID_, 0, 0, 0, 0, NC);
  gate_logits_kernel<<<dim3((N_ + 3) / 4), 256, 0, stream>>>(bufA, gate_W2, gate_b2, logits, N_);
  topk_kernel<<<(N_ + 255) / 256, 256, 0, stream>>>(logits, recept, wsel, N_);

  // ---- top-2 compaction + packed row offsets ----
  hipMemsetAsync(expcnt, 0, 4 * sizeof(int), stream);
  compact_kernel<<<(N_ + 255) / 256, 256, 0, stream>>>(wsel, expidx, posmn, expcnt, N_);
  prefix4_kernel<<<1, 64, 0, stream>>>(expcnt, expoff);

  // ---- experts: batched W1 (packed h in bufA), batched W2 (packed out), combine ----
  gemm13<4, 7, 2><<<dim3(RB, M_, 2), 256, 0, stream>>>(
      bufB, nullptr, exp_W1, exp_b1, bufA, expidx, expcnt, recept, nullptr,
      expoff, N_, C_, HID_, NC, (long long)C_ * HID_, HID_, 0, 0);
  gemm13<5, 9, 0><<<dim3(RB, M_, 1), 256, 0, stream>>>(
      bufA, nullptr, exp_W2, exp_b2, bufB, expidx, expcnt, nullptr, nullptr,
      expoff, N_, HID_, C_, 0, (long long)HID_ * C_, C_, 0, 0);
  combine_kernel<<<(int)(((long long)N_ * 32 + 255) / 256), 256, 0, stream>>>(
      bufB, wsel, posmn, expoff, final_out);
}

// Round 14
// 1262.897 us; speedup vs baseline: 1.5624x; 1.0358x over previous
//
#include <hip/hip_runtime.h>
#include <hip/hip_bf16.h>
#include <math.h>

#define M_  4
#define N_  50000
#define E_  400000
#define IN_ 128
#define C_  128
#define HID_ 256

// ---------------------------------------------------------------------------
// Tiled f32 GEMM: 64 rows x 128 cols, 256 threads, 4x8 micro (R11 optimum;
// R10 8x8 = wave-starved 53% VALU, R13 6x8 = LDS-instr heavy 53%), BK=16
// (midpoint: BK=8 = 2 barriers/256 FMAs, BK=32 spilled at 32 staging regs in
// R6 -- BK=16 stages exactly 3 float4 = 12 regs), single LDS buffer,
// 2 barriers/tile, register prefetch.
// Proven regressions kept reverted: R3 launch_bounds(256,4) acc spill;
// R6 BK=32 staging spill; R9 LDS dbuf VGPR bloat; R12 A-direct-from-global.
// grid = (ceil(R/64), MB, NC/128)
// AMODE 0: A[b*aBatch + r*K + k]
// AMODE 2: A[(k>>7)*strideM + r*128 + (k&127)]      (gate_in view of [M][N][C])
// AMODE 4: batched gather: row=idx[b*N_+r], Reff=cnts[b], AS[b*N_+row]
// AMODE 5: batched packed:  row=roff[b]+r,  Reff=cnts[b]
// ASCALE 0: none  1: relu(AS[(k>>7)*N_+r]*a)  2: relu(AS[row]*a) (AMODE 4)
// EPI 0: store  1: relu-store
// EPI 5: fused grad-map tail -> recept[b*N_+r]
// EPI 6: relu(acc + bias - sub[r*128+c])            (gm_W1: out1@W1 - xd@W1)
// EPI 7: Cmat[(roff[b]+r)*NC+c] = relu(acc+bias)    (batched packed h)
// EPI 9: Cmat[(roff[b]+r)*128+c] = acc+bias         (batched packed out)
// EPI 10: store + fused row-dot: aux[b*N_+r] = (acc+bias) . AS[b*128+c]
//         (xs projection + a_src attention logit, saves 102MB re-read)
// ---------------------------------------------------------------------------
template<int AMODE, int EPI, int ASCALE>
__global__ void __launch_bounds__(256) gemm14(
    const float* A, const float* A2, const float* __restrict__ B,
    const float* __restrict__ bias, float* Cmat,
    const int* __restrict__ idx, const int* __restrict__ cnts,
    const float* __restrict__ AS, const float* __restrict__ fdbuf,
    const int* __restrict__ roff, float* aux,
    int R, int K, int NC,
    long long aBatch, long long bBatch, int biasBatch, long long cBatch,
    long long strideM)
{
  __shared__ float As[16][64];
  __shared__ float Bs[16][128];
  __shared__ float red[(EPI == 5 || EPI == 10) ? 64 * 17 : 1];

  const int tid = threadIdx.x;
  const int b = blockIdx.y;
  const int Reff = (AMODE == 4 || AMODE == 5) ? cnts[b] : (cnts ? cnts[0] : R);
  const int rb = blockIdx.x * 64;
  if (rb >= Reff) return;
  const int cb = blockIdx.z * 128;

  const float* Ab = (AMODE == 2) ? A : (A + (long long)b * aBatch);
  const float* Bb = B + (long long)b * bBatch + cb;
  const float* biasb = bias + (long long)b * biasBatch + cb;

  // A loader: all 256 threads, 64 rows x 16 k = one float4 each
  const int ar = tid >> 2;            // 0..63
  const int ak = (tid & 3) * 4;       // 0,4,8,12
  const int r_a = rb + ar;
  const bool a_ok = (r_a < Reff);
  long long a_row = 0;
  float a_rs = 0.f;
  if (a_ok) {
    if (AMODE == 4) {
      int orow = idx[(long long)b * N_ + r_a];
      a_row = (long long)orow * K;
      if (ASCALE == 2) a_rs = AS[(long long)b * N_ + orow];
    } else if (AMODE == 5) {
      a_row = (long long)(roff[b] + r_a) * K;
    } else if (AMODE == 2) {
      a_row = (long long)r_a * 128;
    } else {
      a_row = (long long)r_a * K;
    }
  }
  // B loader: all 256 threads, 16 k x 128 cols = two float4 each
  const int bk = tid >> 5;            // 0..7 (+8 for second)
  const int bc = (tid & 31) * 4;

  const int tx = tid & 15;
  const int ty = tid >> 4;            // 0..15
  const int fr = ty * 4;              // fragment base row

  float acc[4][8];
  #pragma unroll
  for (int i = 0; i < 4; ++i)
    #pragma unroll
    for (int j = 0; j < 8; ++j) acc[i][j] = 0.f;

  const int nt = K >> 4;
  float4 av = make_float4(0.f, 0.f, 0.f, 0.f), bv0, bv1;

#define LOAD_TILE(k0)                                                          \
  {                                                                            \
    if (a_ok) {                                                                \
      if (AMODE == 2) {                                                        \
        int kk0 = (k0) + ak;                                                   \
        av = *(const float4*)(Ab + (long long)(kk0 >> 7) * strideM + a_row +   \
                              (kk0 & 127));                                    \
        if (ASCALE == 1) {                                                     \
          float rs = AS[(kk0 >> 7) * N_ + r_a];                                \
          av.x = fmaxf(av.x * rs, 0.f); av.y = fmaxf(av.y * rs, 0.f);          \
          av.z = fmaxf(av.z * rs, 0.f); av.w = fmaxf(av.w * rs, 0.f);          \
        }                                                                      \
      } else {                                                                 \
        av = *(const float4*)(Ab + a_row + (k0) + ak);                         \
        if (AMODE == 4 && ASCALE == 2) {                                       \
          av.x = fmaxf(av.x * a_rs, 0.f); av.y = fmaxf(av.y * a_rs, 0.f);      \
          av.z = fmaxf(av.z * a_rs, 0.f); av.w = fmaxf(av.w * a_rs, 0.f);      \
        }                                                                      \
      }                                                                        \
    } else {                                                                   \
      av = make_float4(0.f, 0.f, 0.f, 0.f);                                    \
    }                                                                          \
    bv0 = *(const float4*)(Bb + (long long)((k0) + bk) * NC + bc);             \
    bv1 = *(const float4*)(Bb + (long long)((k0) + bk + 8) * NC + bc);         \
  }

  // stage tile 0
  LOAD_TILE(0)

  for (int t = 0; t < nt; ++t) {
    __syncthreads();   // readers of LDS (tile t-1) done
    As[ak + 0][ar] = av.x; As[ak + 1][ar] = av.y;
    As[ak + 2][ar] = av.z; As[ak + 3][ar] = av.w;
    *(float4*)(&Bs[bk][bc]) = bv0;
    *(float4*)(&Bs[bk + 8][bc]) = bv1;
    __syncthreads();   // tile t visible

    // prefetch tile t+1: loads retire under the 512-FMA block below
    if (t + 1 < nt) LOAD_TILE((t + 1) * 16)

    #pragma unroll
    for (int kk = 0; kk < 16; ++kk) {
      float4 a4 = *(float4*)(&As[kk][fr]);
      float4 blo = *(float4*)(&Bs[kk][tx * 4]);
      float4 bhi = *(float4*)(&Bs[kk][64 + tx * 4]);
      float a_[4] = {a4.x, a4.y, a4.z, a4.w};
      float b8[8] = {blo.x, blo.y, blo.z, blo.w, bhi.x, bhi.y, bhi.z, bhi.w};
      #pragma unroll
      for (int i = 0; i < 4; ++i)
        #pragma unroll
        for (int j = 0; j < 8; ++j)
          acc[i][j] += a_[i] * b8[j];
    }
  }
#undef LOAD_TILE

  if (EPI == 5) {
    // fused: mo = sigmoid(acc+bias); gd = mean_c(mo * (out1 - xd)); recept
    #pragma unroll
    for (int i = 0; i < 4; ++i) {
      const int r_local = fr + i;
      const int r = rb + r_local;
      if (r < Reff) {
        const float* fdrow = fdbuf + (long long)b * cBatch + (long long)r * 128;
        const float* xdrow = A2 + (long long)r * 128;
        float4 flo = *(const float4*)(fdrow + tx * 4);
        float4 fhi = *(const float4*)(fdrow + 64 + tx * 4);
        float4 xlo = *(const float4*)(xdrow + tx * 4);
        float4 xhi = *(const float4*)(xdrow + 64 + tx * 4);
        float fd8[8] = {flo.x - xlo.x, flo.y - xlo.y, flo.z - xlo.z, flo.w - xlo.w,
                        fhi.x - xhi.x, fhi.y - xhi.y, fhi.z - xhi.z, fhi.w - xhi.w};
        float p = 0.f;
        #pragma unroll
        for (int j = 0; j < 8; ++j) {
          const int c = (j < 4 ? tx * 4 + j : 64 + tx * 4 + (j - 4));
          float mo = 1.f / (1.f + expf(-(acc[i][j] + biasb[c])));
          p += mo * fd8[j];
        }
        red[r_local * 17 + tx] = p;
      }
    }
    __syncthreads();
    if (tid < 64) {
      const int r = rb + tid;
      if (r < Reff) {
        float s = 0.f;
        #pragma unroll
        for (int t = 0; t < 16; ++t) s += red[tid * 17 + t];
        float gd = s / 128.f;
        Cmat[(long long)b * N_ + r] = gd / (fabsf(gd) + 1e-8f);
      }
    }
    return;
  }

  #pragma unroll
  for (int i = 0; i < 4; ++i) {
    const int r = rb + fr + i;
    if (r >= Reff) continue;
    long long crow;
    if (EPI == 7) crow = (long long)(roff[b] + r) * NC + cb;
    else if (EPI == 9) crow = (long long)(roff[b] + r) * 128 + cb;
    else crow = (long long)b * cBatch + (long long)r * NC + cb;
    const float* subrow = (EPI == 6) ? (fdbuf + (long long)r * 128 + cb) : nullptr;
    float p = 0.f;
    #pragma unroll
    for (int j = 0; j < 8; ++j) {
      const int c = (j < 4 ? tx * 4 + j : 64 + tx * 4 + (j - 4));
      float v = acc[i][j] + biasb[c];
      if (EPI == 6) v = fmaxf(v - subrow[c], 0.f);
      if (EPI == 1 || EPI == 7) v = fmaxf(v, 0.f);
      Cmat[crow + c] = v;
      if (EPI == 10) p += v * AS[(long long)b * 128 + c];
    }
    if (EPI == 10) red[(fr + i) * 17 + tx] = p;
  }
  if (EPI == 10) {
    __syncthreads();
    if (tid < 64) {
      const int r = rb + tid;
      if (r < Reff) {
        float s = 0.f;
        #pragma unroll
        for (int t = 0; t < 16; ++t) s += red[tid * 17 + t];
        aux[(long long)b * N_ + r] = s;
      }
    }
  }
}

// a[m*Nn + n] = dot(X[n], lin[m*128 ..])  (xd/adst only)
__global__ void attn_logit_kernel(const float* __restrict__ X, const float* __restrict__ lin,
                                  float* __restrict__ out, int Nn)
{
  int m = blockIdx.y;
  int w = blockIdx.x * (blockDim.x >> 6) + (threadIdx.x >> 6);
  int lane = threadIdx.x & 63;
  if (w >= Nn) return;
  const float* xr = X + (long long)w * 128;
  const float* lr = lin + m * 128;
  float acc = xr[lane] * lr[lane] + xr[lane + 64] * lr[lane + 64];
  #pragma unroll
  for (int off = 32; off > 0; off >>= 1) acc += __shfl_down(acc, off);
  if (lane == 0) out[(long long)m * Nn + w] = acc;
}

// ---- CSR build ----
__global__ void count_kernel(const int* __restrict__ dst, int* __restrict__ cnt, int Nn)
{
  int e = blockIdx.x * blockDim.x + threadIdx.x;
  int m = blockIdx.y;
  if (e >= E_) return;
  atomicAdd(&cnt[(long long)m * Nn + dst[(long long)m * E_ + e]], 1);
}

// 3-phase wide scan
__global__ void chunkscan_kernel(const int* __restrict__ cnt, int* __restrict__ rowptr,
                                 int* __restrict__ chunktot)
{
  int m = blockIdx.y, ch = blockIdx.x;
  int base = ch * 1024;
  const int* c = cnt + (long long)m * N_;
  int* rp = rowptr + (long long)m * (N_ + 1);
  __shared__ int sums[256];
  int t = threadIdx.x;
  int v[4]; int s = 0;
  #pragma unroll
  for (int k = 0; k < 4; ++k) {
    int i = base + t * 4 + k;
    v[k] = (i < N_) ? c[i] : 0;
    s += v[k];
  }
  sums[t] = s;
  __syncthreads();
  for (int off = 1; off < 256; off <<= 1) {
    int x = (t >= off) ? sums[t - off] : 0;
    __syncthreads();
    sums[t] += x;
    __syncthreads();
  }
  int run = sums[t] - s;
  #pragma unroll
  for (int k = 0; k < 4; ++k) {
    int i = base + t * 4 + k;
    run += v[k];
    if (i < N_) rp[i + 1] = run;
  }
  if (t == 255) chunktot[m * 64 + ch] = sums[255];
}

__global__ void scantot_kernel(int* __restrict__ chunktot, int nch)
{
  int m = threadIdx.x;
  if (m >= M_) return;
  int run = 0;
  for (int ch = 0; ch < nch; ++ch) {
    int v = chunktot[m * 64 + ch];
    chunktot[m * 64 + ch] = run;
    run += v;
  }
}

__global__ void addoff_kernel(int* __restrict__ rowptr, const int* __restrict__ chunktot)
{
  int m = blockIdx.y, ch = blockIdx.x;
  int off = chunktot[m * 64 + ch];
  int t = threadIdx.x;
  int* rp = rowptr + (long long)m * (N_ + 1);
  #pragma unroll
  for (int k = 0; k < 4; ++k) {
    int i = ch * 1024 + t * 4 + k;
    if (i < N_) rp[i + 1] += off;
  }
  if (ch == 0 && t == 0) rp[0] = 0;
}

__global__ void scatter_kernel(const int* __restrict__ dst, const int* __restrict__ rowptr,
                               int* __restrict__ fill, int* __restrict__ col, int Nn)
{
  int e = blockIdx.x * blockDim.x + threadIdx.x;
  int m = blockIdx.y;
  if (e >= E_) return;
  int d = dst[(long long)m * E_ + e];
  int pos = rowptr[(long long)m * (Nn + 1) + d] + atomicAdd(&fill[(long long)m * Nn + d], 1);
  col[(long long)m * E_ + pos] = e;
}

__global__ void sortbucket_kernel(const int* __restrict__ rowptr, int* __restrict__ col, int Nn)
{
  int n = blockIdx.x * blockDim.x + threadIdx.x;
  int m = blockIdx.y;
  if (n >= Nn) return;
  const int* rp = rowptr + (long long)m * (Nn + 1);
  int* c = col + (long long)m * E_;
  int b = rp[n], e = rp[n + 1];
  for (int i = b + 1; i < e; ++i) {
    int v = c[i]; int j = i - 1;
    while (j >= b && c[j] > v) { c[j + 1] = c[j]; --j; }
    c[j + 1] = v;
  }
}

// per-edge attention logit, edge-parallel
__global__ void edge_e_kernel(const int* __restrict__ src, const int* __restrict__ dst,
                              const float* __restrict__ asrc, const float* __restrict__ adst,
                              float* __restrict__ e_edge)
{
  int e = blockIdx.x * blockDim.x + threadIdx.x;
  int m = blockIdx.y;
  if (e >= E_) return;
  long long off = (long long)m * E_ + e;
  float v = asrc[(long long)m * N_ + src[off]] + adst[(long long)m * N_ + dst[off]];
  e_edge[off] = (v >= 0.f) ? v : 0.2f * v;
}

// per-node softmax over its bucket -> alpha + src id in CSR order
__global__ void alpha_kernel(const int* __restrict__ rowptr, const int* __restrict__ col,
                             const int* __restrict__ src, const float* __restrict__ e_edge,
                             float* __restrict__ alpha, int* __restrict__ src_csr)
{
  int n = blockIdx.x * blockDim.x + threadIdx.x;
  int m = blockIdx.y;
  if (n >= N_) return;
  const int* rp = rowptr + (long long)m * (N_ + 1);
  const int* cl = col + (long long)m * E_;
  const int* sr = src + (long long)m * E_;
  const float* ee = e_edge + (long long)m * E_;
  float* al = alpha + (long long)m * E_;
  int* sc = src_csr + (long long)m * E_;
  int b = rp[n], en = rp[n + 1];
  if (b == en) return;
  float emax = -INFINITY;
  for (int j = b; j < en; ++j) emax = fmaxf(emax, ee[cl[j]]);
  float den = 0.f;
  for (int j = b; j < en; ++j) {
    int eid = cl[j];
    float ez = expf(ee[eid] - emax);
    den += ez;
    al[j] = ez;
    sc[j] = sr[eid];
  }
  float inv = 1.f / (den + 1e-16f);
  for (int j = b; j < en; ++j) al[j] *= inv;
}

// heavy gather: out1[d] = sum_j alpha[j] * xs[src_csr[j]]; 2 dst per block
__global__ void prop2_kernel(const float* __restrict__ xs, const int* __restrict__ rowptr,
                             const float* __restrict__ alpha, const int* __restrict__ src_csr,
                             float* __restrict__ out)
{
  int d = blockIdx.x * 2 + (threadIdx.x >> 7);
  int m = blockIdx.y;
  int c = threadIdx.x & 127;
  if (d >= N_) return;
  const int* rp = rowptr + (long long)m * (N_ + 1);
  const float* al = alpha + (long long)m * E_;
  const int* sc = src_csr + (long long)m * E_;
  const float* xsm = xs + (long long)m * N_ * 128;
  int b = rp[d], en = rp[d + 1];
  float acc = 0.f;
  int j = b;
  for (; j + 3 < en; j += 4) {
    float a0 = al[j], a1 = al[j + 1], a2 = al[j + 2], a3 = al[j + 3];
    int s0 = sc[j], s1 = sc[j + 1], s2 = sc[j + 2], s3 = sc[j + 3];
    float x0 = xsm[(long long)s0 * 128 + c];
    float x1 = xsm[(long long)s1 * 128 + c];
    float x2 = xsm[(long long)s2 * 128 + c];
    float x3 = xsm[(long long)s3 * 128 + c];
    acc += a0 * x0; acc += a1 * x1; acc += a2 * x2; acc += a3 * x3;
  }
  for (; j < en; ++j)
    acc += al[j] * xsm[(long long)sc[j] * 128 + c];
  out[((long long)m * N_ + d) * 128 + c] = acc;
}

// logits[n, 0..3] = h[n,0..255] @ W2[256,4] + b2
__global__ void gate_logits_kernel(const float* __restrict__ h, const float* __restrict__ W2,
                                   const float* __restrict__ b2, float* __restrict__ logits, int Nn)
{
  int w = blockIdx.x * (blockDim.x >> 6) + (threadIdx.x >> 6);
  int lane = threadIdx.x & 63;
  if (w >= Nn) return;
  const float* hr = h + (long long)w * 256;
  float a0 = 0.f, a1 = 0.f, a2 = 0.f, a3 = 0.f;
  for (int j = lane; j < 256; j += 64) {
    float hv = hr[j];
    a0 += hv * W2[j * 4 + 0];
    a1 += hv * W2[j * 4 + 1];
    a2 += hv * W2[j * 4 + 2];
    a3 += hv * W2[j * 4 + 3];
  }
  #pragma unroll
  for (int off = 32; off > 0; off >>= 1) {
    a0 += __shfl_down(a0, off);
    a1 += __shfl_down(a1, off);
    a2 += __shfl_down(a2, off);
    a3 += __shfl_down(a3, off);
  }
  if (lane == 0) {
    long long o = (long long)w * 4;
    logits[o + 0] = a0 + b2[0];
    logits[o + 1] = a1 + b2[1];
    logits[o + 2] = a2 + b2[2];
    logits[o + 3] = a3 + b2[3];
  }
}

// softmax + recept.T + top-2 (ties: lower index) -> wsel[M,N]
__global__ void topk_kernel(const float* __restrict__ logits, const float* __restrict__ recept,
                            float* __restrict__ wsel, int Nn)
{
  int n = blockIdx.x * blockDim.x + threadIdx.x;
  if (n >= Nn) return;
  float l[4];
  #pragma unroll
  for (int m = 0; m < 4; ++m) l[m] = logits[(long long)n * 4 + m];
  float mx = fmaxf(fmaxf(l[0], l[1]), fmaxf(l[2], l[3]));
  float e[4], s = 0.f;
  #pragma unroll
  for (int m = 0; m < 4; ++m) { e[m] = expf(l[m] - mx); s += e[m]; }
  float sc[4];
  #pragma unroll
  for (int m = 0; m < 4; ++m) sc[m] = e[m] / s + recept[(long long)m * Nn + n];
  int i0 = 0; float v0 = sc[0];
  #pragma unroll
  for (int m = 1; m < 4; ++m) if (sc[m] > v0) { v0 = sc[m]; i0 = m; }
  int i1 = -1; float v1 = -INFINITY;
  #pragma unroll
  for (int m = 0; m < 4; ++m) { if (m == i0) continue; if (sc[m] > v1) { v1 = sc[m]; i1 = m; } }
  float ts = v0 + v1;
  float w0 = v0 / ts, w1 = v1 / ts;
  #pragma unroll
  for (int m = 0; m < 4; ++m)
    wsel[(long long)m * Nn + n] = (m == i0) ? w0 : ((m == i1) ? w1 : 0.f);
}

// compaction + record packed position per (m,n)
__global__ void compact_kernel(const float* __restrict__ wsel, int* __restrict__ idx,
                               int* __restrict__ posmn, int* __restrict__ cnts, int Nn)
{
  int n = blockIdx.x * blockDim.x + threadIdx.x;
  if (n >= Nn) return;
  #pragma unroll
  for (int m = 0; m < 4; ++m) {
    if (wsel[(long long)m * Nn + n] != 0.f) {
      int p = atomicAdd(&cnts[m], 1);
      idx[(long long)m * Nn + p] = n;
      posmn[(long long)m * Nn + n] = p;
    }
  }
}

__global__ void prefix4_kernel(const int* __restrict__ cnts, int* __restrict__ off)
{
  if (threadIdx.x == 0) {
    int r = 0;
    #pragma unroll
    for (int m = 0; m < 4; ++m) { off[m] = r; r += cnts[m]; }
  }
}

// final[n] = sum_m wsel[m,n] * outp[(expoff[m]+posmn[m,n])*128 + c]
__global__ void combine_kernel(const float* __restrict__ outp, const float* __restrict__ wsel,
                               const int* __restrict__ posmn, const int* __restrict__ expoff,
                               float* __restrict__ fin)
{
  long long i = (long long)blockIdx.x * blockDim.x + threadIdx.x;
  if (i >= (long long)N_ * 32) return;
  int n = (int)(i >> 5);
  int c4 = (int)(i & 31) * 4;
  float4 acc = make_float4(0.f, 0.f, 0.f, 0.f);
  #pragma unroll
  for (int m = 0; m < 4; ++m) {
    float w = wsel[(long long)m * N_ + n];
    if (w != 0.f) {
      int p = expoff[m] + posmn[(long long)m * N_ + n];
      float4 v = *(const float4*)(outp + (long long)p * 128 + c4);
      acc.x += w * v.x; acc.y += w * v.y; acc.z += w * v.z; acc.w += w * v.w;
    }
  }
  *(float4*)(fin + (long long)n * 128 + c4) = acc;
}

extern "C" void kernel_launch(void* const* d_in, const int* in_sizes, int n_in,
                              void* d_out, int out_size, void* d_ws, size_t ws_size,
                              hipStream_t stream) {
  const float* x_src   = (const float*)d_in[0];
  const float* x_dst   = (const float*)d_in[1];
  const int*   src_idx = (const int*)d_in[2];
  const int*   dst_idx = (const int*)d_in[3];
  const float* proj_Ws = (const float*)d_in[4];
  const float* proj_bs = (const float*)d_in[5];
  const float* projd_W = (const float*)d_in[6];
  const float* projd_b = (const float*)d_in[7];
  const float* lin_src = (const float*)d_in[8];
  const float* lin_dst = (const float*)d_in[9];
  const float* gm_W1   = (const float*)d_in[10];
  const float* gm_b1   = (const float*)d_in[11];
  const float* gm_W2   = (const float*)d_in[12];
  const float* gm_b2   = (const float*)d_in[13];
  const float* gate_W1 = (const float*)d_in[14];
  const float* gate_b1 = (const float*)d_in[15];
  const float* gate_W2 = (const float*)d_in[16];
  const float* gate_b2 = (const float*)d_in[17];
  const float* exp_W1  = (const float*)d_in[18];
  const float* exp_b1  = (const float*)d_in[19];
  const float* exp_W2  = (const float*)d_in[20];
  const float* exp_b2  = (const float*)d_in[21];
  float* final_out = (float*)d_out;

  float* ws = (float*)d_ws;
  float* bufA   = ws;                        // [M,N,128]: xs -> h1 -> gate-h -> packed expert-h
  float* bufB   = ws + 25600000LL;           // [M,N,128]: out1 ; later packed expert-out
  float* xd     = ws + 51200000LL;           // [N,128]
  float* asrc   = ws + 57600000LL;           // [M,N]
  float* adst   = ws + 57800000LL;           // [M,N]
  float* recept = ws + 58000000LL;           // [M,N]
  float* wsel   = ws + 58200000LL;           // [M,N]
  float* logits = ws + 58400000LL;           // [N,4]
  float* e_edge = ws + 58600000LL;           // [M,E]
  float* alpha  = ws + 60200000LL;           // [M,E]
  float* xdW1   = ws + 61800000LL;           // [N,128]
  float* zbuf   = ws + 68200000LL;           // [128] zeros
  int*   ibase  = (int*)(ws + 68300000LL);
  int*   rowptr = ibase;                     // [M,(N+1)]
  int*   col    = ibase + 200004;            // [M,E]
  int*   cnt    = ibase + 1800004;           // [M,N]
  int*   expidx = cnt;                       // reuse after CSR build
  int*   expcnt = ibase + 2000004;           // [4]
  int*   src_csr= ibase + 2000008;           // [M,E]
  int*   chunktot = ibase + 3600008;         // [M,64]
  int*   expoff = ibase + 3600264;           // [4]
  int*   posmn  = ibase + 3600268;           // [M,N]

  const long long NC = (long long)N_ * C_;
  const int RB = (N_ + 63) / 64;             // 782 row blocks
  const int NCH = (N_ + 1023) / 1024;        // 49

  // ---- CSR build ----
  hipMemsetAsync(cnt, 0, (size_t)M_ * N_ * sizeof(int), stream);
  hipMemsetAsync(zbuf, 0, 128 * sizeof(float), stream);
  count_kernel<<<dim3((E_ + 255) / 256, M_), 256, 0, stream>>>(dst_idx, cnt, N_);
  chunkscan_kernel<<<dim3(NCH, M_), 256, 0, stream>>>(cnt, rowptr, chunktot);
  scantot_kernel<<<1, 64, 0, stream>>>(chunktot, NCH);
  addoff_kernel<<<dim3(NCH, M_), 256, 0, stream>>>(rowptr, chunktot);
  hipMemsetAsync(cnt, 0, (size_t)M_ * N_ * sizeof(int), stream);
  scatter_kernel<<<dim3((E_ + 255) / 256, M_), 256, 0, stream>>>(dst_idx, rowptr, cnt, col, N_);
  sortbucket_kernel<<<dim3((N_ + 255) / 256, M_), 256, 0, stream>>>(rowptr, col, N_);

  // ---- xd = x_dst @ projd_W + b ----
  gemm14<0, 0, 0><<<dim3(RB, 1, 1), 256, 0, stream>>>(
      x_dst, nullptr, projd_W, projd_b, xd, nullptr, nullptr, nullptr, nullptr,
      nullptr, nullptr, N_, IN_, C_, 0, 0, 0, 0, 0);
  attn_logit_kernel<<<dim3((N_ + 3) / 4, M_), 256, 0, stream>>>(xd, lin_dst, adst, N_);

  // ---- xdW1 = xd @ gm_W1 (zero bias) ----
  gemm14<0, 0, 0><<<dim3(RB, 1, 1), 256, 0, stream>>>(
      xd, nullptr, gm_W1, zbuf, xdW1, nullptr, nullptr, nullptr, nullptr,
      nullptr, nullptr, N_, C_, C_, 0, 0, 0, 0, 0);

  // ---- xs = per-type projection (batched) + fused a_src row-dot ----
  gemm14<0, 10, 0><<<dim3(RB, M_, 1), 256, 0, stream>>>(
      x_src, nullptr, proj_Ws, proj_bs, bufA, nullptr, nullptr, lin_src, nullptr,
      nullptr, asrc, N_, IN_, C_, NC, (long long)IN_ * C_, C_, NC, 0);

  // ---- attention softmax precompute ----
  edge_e_kernel<<<dim3((E_ + 255) / 256, M_), 256, 0, stream>>>(
      src_idx, dst_idx, asrc, adst, e_edge);
  alpha_kernel<<<dim3((N_ + 255) / 256, M_), 256, 0, stream>>>(
      rowptr, col, src_idx, e_edge, alpha, src_csr);

  // ---- propagation (single gather pass) -> out1 in bufB ----
  prop2_kernel<<<dim3((N_ + 1) / 2, M_), 256, 0, stream>>>(bufA, rowptr, alpha, src_csr, bufB);

  // ---- grad-map MLP: h1 = relu(out1@W1 + b1 - xdW1); fused W2 tail -> recept ----
  gemm14<0, 6, 0><<<dim3(RB, M_, 1), 256, 0, stream>>>(
      bufB, nullptr, gm_W1, gm_b1, bufA, nullptr, nullptr, nullptr, xdW1,
      nullptr, nullptr, N_, C_, C_, NC, 0, 0, NC, 0);
  gemm14<0, 5, 0><<<dim3(RB, M_, 1), 256, 0, stream>>>(
      bufA, xd, gm_W2, gm_b2, recept, nullptr, nullptr, nullptr, bufB,
      nullptr, nullptr, N_, C_, C_, NC, 0, 0, NC, 0);

  // ---- gate: h = relu(gate_in @ W1 + b1); feats fused on A-load ----
  gemm14<2, 1, 1><<<dim3(RB, 1, 2), 256, 0, stream>>>(
      bufB, nullptr, gate_W1, gate_b1, bufA, nullptr, nullptr, recept, nullptr,
      nullptr, nullptr, N_, M_ * C_, HID_, 0, 0, 0, 0, NC);
  gate_logits_kernel<<<dim3((N_ + 3) / 4), 256, 0, stream>>>(bufA, gate_W2, gate_b2, logits, N_);
  topk_kernel<<<(N_ + 255) / 256, 256, 0, stream>>>(logits, recept, wsel, N_);

  // ---- top-2 compaction + packed row offsets ----
  hipMemsetAsync(expcnt, 0, 4 * sizeof(int), stream);
  compact_kernel<<<(N_ + 255) / 256, 256, 0, stream>>>(wsel, expidx, posmn, expcnt, N_);
  prefix4_kernel<<<1, 64, 0, stream>>>(expcnt, expoff);

  // ---- experts: batched W1 (packed h in bufA), batched W2 (packed out), combine ----
  gemm14<4, 7, 2><<<dim3(RB, M_, 2), 256, 0, stream>>>(
      bufB, nullptr, exp_W1, exp_b1, bufA, expidx, expcnt, recept, nullptr,
      expoff, nullptr, N_, C_, HID_, NC, (long long)C_ * HID_, HID_, 0, 0);
  gemm14<5, 9, 0><<<dim3(RB, M_, 1), 256, 0, stream>>>(
      bufA, nullptr, exp_W2, exp_b2, bufB, expidx, expcnt, nullptr, nullptr,
      expoff, nullptr, N_, HID_, C_, 0, (long long)HID_ * C_, C_, 0, 0);
  combine_kernel<<<(int)(((long long)N_ * 32 + 255) / 256), 256, 0, stream>>>(
      bufB, wsel, posmn, expoff, final_out);
}

// Round 15
// 1247.934 us; speedup vs baseline: 1.5812x; 1.0120x over previous
//
#include <hip/hip_runtime.h>
#include <hip/hip_bf16.h>
#include <math.h>

#define M_  4
#define N_  50000
#define E_  400000
#define IN_ 128
#define C_  128
#define HID_ 256

// ---------------------------------------------------------------------------
// Tiled f32 GEMM: 64 rows x 128 cols, 256 threads, 4x8 micro, BK=8,
// single LDS buffer, 2 barriers/tile, 8-VGPR register prefetch.
// This is the bracketed optimum of the tile-space search:
//   R10 8x8@128^2: 12.2 waves/CU cap, VALU 53%   (wave-starved)
//   R11 4x8@64x128: 24 waves/CU, VALU 60%        <-- core kept here
//   R13 6x8@96x128: VALU 53%                     (LDS-instr heavy)
//   R14 BK=16: bank conflicts 3x (ar=tid>>2 -> 16 banks, 4-way), occ 31%
// Proven regressions kept reverted: R3 launch_bounds(256,4) acc spill;
// R6 BK=32 staging spill; R9 LDS dbuf VGPR bloat; R12 A-direct-from-global.
// grid = (ceil(R/64), MB, NC/128)
// AMODE 0: A[b*aBatch + r*K + k]
// AMODE 2: A[(k>>7)*strideM + r*128 + (k&127)]      (gate_in view of [M][N][C])
// AMODE 4: batched gather: row=idx[b*N_+r], Reff=cnts[b], AS[b*N_+row]
// AMODE 5: batched packed:  row=roff[b]+r,  Reff=cnts[b]
// ASCALE 0: none  1: relu(AS[(k>>7)*N_+r]*a)  2: relu(AS[row]*a) (AMODE 4)
// EPI 0: store  1: relu-store
// EPI 5: fused grad-map tail -> recept[b*N_+r]
// EPI 6: relu(acc + bias - sub[r*128+c])            (gm_W1: out1@W1 - xd@W1)
// EPI 7: Cmat[(roff[b]+r)*NC+c] = relu(acc+bias)    (batched packed h)
// EPI 9: Cmat[(roff[b]+r)*128+c] = acc+bias         (batched packed out)
// EPI 10: store + fused row-dot: aux[b*N_+r] = (acc+bias) . AS[b*128+..]
//         (xs projection + a_src attention logit, saves 102MB re-read)
// ---------------------------------------------------------------------------
template<int AMODE, int EPI, int ASCALE>
__global__ void __launch_bounds__(256) gemm15(
    const float* A, const float* A2, const float* __restrict__ B,
    const float* __restrict__ bias, float* Cmat,
    const int* __restrict__ idx, const int* __restrict__ cnts,
    const float* __restrict__ AS, const float* __restrict__ fdbuf,
    const int* __restrict__ roff, float* aux,
    int R, int K, int NC,
    long long aBatch, long long bBatch, int biasBatch, long long cBatch,
    long long strideM)
{
  __shared__ float As[8][64];
  __shared__ float Bs[8][128];
  __shared__ float red[(EPI == 5 || EPI == 10) ? 64 * 17 : 1];

  const int tid = threadIdx.x;
  const int b = blockIdx.y;
  const int Reff = (AMODE == 4 || AMODE == 5) ? cnts[b] : (cnts ? cnts[0] : R);
  const int rb = blockIdx.x * 64;
  if (rb >= Reff) return;
  const int cb = blockIdx.z * 128;

  const float* Ab = (AMODE == 2) ? A : (A + (long long)b * aBatch);
  const float* Bb = B + (long long)b * bBatch + cb;
  const float* biasb = bias + (long long)b * biasBatch + cb;

  // A loader: first 128 threads, 64 rows x 8 k, one float4 each
  const int ar = tid >> 1;            // 0..63 (tid<128)
  const int ak = (tid & 1) * 4;       // 0 or 4
  const int r_a = rb + ar;
  const bool a_ok = (tid < 128) && (r_a < Reff);
  long long a_row = 0;
  float a_rs = 0.f;
  if (a_ok) {
    if (AMODE == 4) {
      int orow = idx[(long long)b * N_ + r_a];
      a_row = (long long)orow * K;
      if (ASCALE == 2) a_rs = AS[(long long)b * N_ + orow];
    } else if (AMODE == 5) {
      a_row = (long long)(roff[b] + r_a) * K;
    } else if (AMODE == 2) {
      a_row = (long long)r_a * 128;
    } else {
      a_row = (long long)r_a * K;
    }
  }
  // B loader: all 256 threads, 8 k x 128 cols, one float4 each
  const int bk = tid >> 5;
  const int bc = (tid & 31) * 4;

  const int tx = tid & 15;
  const int ty = tid >> 4;            // 0..15
  const int fr = ty * 4;              // fragment base row

  float acc[4][8];
  #pragma unroll
  for (int i = 0; i < 4; ++i)
    #pragma unroll
    for (int j = 0; j < 8; ++j) acc[i][j] = 0.f;

  const int nt = K >> 3;
  float4 av = make_float4(0.f, 0.f, 0.f, 0.f), bv;

#define LOAD_TILE(k0)                                                          \
  {                                                                            \
    if (a_ok) {                                                                \
      if (AMODE == 2) {                                                        \
        int kk0 = (k0) + ak;                                                   \
        av = *(const float4*)(Ab + (long long)(kk0 >> 7) * strideM + a_row +   \
                              (kk0 & 127));                                    \
        if (ASCALE == 1) {                                                     \
          float rs = AS[(kk0 >> 7) * N_ + r_a];                                \
          av.x = fmaxf(av.x * rs, 0.f); av.y = fmaxf(av.y * rs, 0.f);          \
          av.z = fmaxf(av.z * rs, 0.f); av.w = fmaxf(av.w * rs, 0.f);          \
        }                                                                      \
      } else {                                                                 \
        av = *(const float4*)(Ab + a_row + (k0) + ak);                         \
        if (AMODE == 4 && ASCALE == 2) {                                       \
          av.x = fmaxf(av.x * a_rs, 0.f); av.y = fmaxf(av.y * a_rs, 0.f);      \
          av.z = fmaxf(av.z * a_rs, 0.f); av.w = fmaxf(av.w * a_rs, 0.f);      \
        }                                                                      \
      }                                                                        \
    } else {                                                                   \
      av = make_float4(0.f, 0.f, 0.f, 0.f);                                    \
    }                                                                          \
    bv = *(const float4*)(Bb + (long long)((k0) + bk) * NC + bc);              \
  }

  // stage tile 0
  LOAD_TILE(0)

  for (int t = 0; t < nt; ++t) {
    __syncthreads();   // readers of LDS (tile t-1) done
    if (tid < 128) {
      As[ak + 0][ar] = av.x; As[ak + 1][ar] = av.y;
      As[ak + 2][ar] = av.z; As[ak + 3][ar] = av.w;
    }
    *(float4*)(&Bs[bk][bc]) = bv;
    __syncthreads();   // tile t visible

    // prefetch tile t+1: loads retire under the FMA block below
    if (t + 1 < nt) LOAD_TILE((t + 1) * 8)

    #pragma unroll
    for (int kk = 0; kk < 8; ++kk) {
      float4 a4 = *(float4*)(&As[kk][fr]);
      float4 blo = *(float4*)(&Bs[kk][tx * 4]);
      float4 bhi = *(float4*)(&Bs[kk][64 + tx * 4]);
      float a_[4] = {a4.x, a4.y, a4.z, a4.w};
      float b8[8] = {blo.x, blo.y, blo.z, blo.w, bhi.x, bhi.y, bhi.z, bhi.w};
      #pragma unroll
      for (int i = 0; i < 4; ++i)
        #pragma unroll
        for (int j = 0; j < 8; ++j)
          acc[i][j] += a_[i] * b8[j];
    }
  }
#undef LOAD_TILE

  if (EPI == 5) {
    // fused: mo = sigmoid(acc+bias); gd = mean_c(mo * (out1 - xd)); recept
    #pragma unroll
    for (int i = 0; i < 4; ++i) {
      const int r_local = fr + i;
      const int r = rb + r_local;
      if (r < Reff) {
        const float* fdrow = fdbuf + (long long)b * cBatch + (long long)r * 128;
        const float* xdrow = A2 + (long long)r * 128;
        float4 flo = *(const float4*)(fdrow + tx * 4);
        float4 fhi = *(const float4*)(fdrow + 64 + tx * 4);
        float4 xlo = *(const float4*)(xdrow + tx * 4);
        float4 xhi = *(const float4*)(xdrow + 64 + tx * 4);
        float fd8[8] = {flo.x - xlo.x, flo.y - xlo.y, flo.z - xlo.z, flo.w - xlo.w,
                        fhi.x - xhi.x, fhi.y - xhi.y, fhi.z - xhi.z, fhi.w - xhi.w};
        float p = 0.f;
        #pragma unroll
        for (int j = 0; j < 8; ++j) {
          const int c = (j < 4 ? tx * 4 + j : 64 + tx * 4 + (j - 4));
          float mo = 1.f / (1.f + expf(-(acc[i][j] + biasb[c])));
          p += mo * fd8[j];
        }
        red[r_local * 17 + tx] = p;
      }
    }
    __syncthreads();
    if (tid < 64) {
      const int r = rb + tid;
      if (r < Reff) {
        float s = 0.f;
        #pragma unroll
        for (int t = 0; t < 16; ++t) s += red[tid * 17 + t];
        float gd = s / 128.f;
        Cmat[(long long)b * N_ + r] = gd / (fabsf(gd) + 1e-8f);
      }
    }
    return;
  }

  #pragma unroll
  for (int i = 0; i < 4; ++i) {
    const int r = rb + fr + i;
    if (r >= Reff) continue;
    long long crow;
    if (EPI == 7) crow = (long long)(roff[b] + r) * NC + cb;
    else if (EPI == 9) crow = (long long)(roff[b] + r) * 128 + cb;
    else crow = (long long)b * cBatch + (long long)r * NC + cb;
    const float* subrow = (EPI == 6) ? (fdbuf + (long long)r * 128 + cb) : nullptr;
    float p = 0.f;
    #pragma unroll
    for (int j = 0; j < 8; ++j) {
      const int c = (j < 4 ? tx * 4 + j : 64 + tx * 4 + (j - 4));
      float v = acc[i][j] + biasb[c];
      if (EPI == 6) v = fmaxf(v - subrow[c], 0.f);
      if (EPI == 1 || EPI == 7) v = fmaxf(v, 0.f);
      Cmat[crow + c] = v;
      if (EPI == 10) p += v * AS[(long long)b * 128 + c];
    }
    if (EPI == 10) red[(fr + i) * 17 + tx] = p;
  }
  if (EPI == 10) {
    __syncthreads();
    if (tid < 64) {
      const int r = rb + tid;
      if (r < Reff) {
        float s = 0.f;
        #pragma unroll
        for (int t = 0; t < 16; ++t) s += red[tid * 17 + t];
        aux[(long long)b * N_ + r] = s;
      }
    }
  }
}

// a[m*Nn + n] = dot(X[n], lin[m*128 ..])  (xd/adst only)
__global__ void attn_logit_kernel(const float* __restrict__ X, const float* __restrict__ lin,
                                  float* __restrict__ out, int Nn)
{
  int m = blockIdx.y;
  int w = blockIdx.x * (blockDim.x >> 6) + (threadIdx.x >> 6);
  int lane = threadIdx.x & 63;
  if (w >= Nn) return;
  const float* xr = X + (long long)w * 128;
  const float* lr = lin + m * 128;
  float acc = xr[lane] * lr[lane] + xr[lane + 64] * lr[lane + 64];
  #pragma unroll
  for (int off = 32; off > 0; off >>= 1) acc += __shfl_down(acc, off);
  if (lane == 0) out[(long long)m * Nn + w] = acc;
}

// ---- CSR build ----
__global__ void count_kernel(const int* __restrict__ dst, int* __restrict__ cnt, int Nn)
{
  int e = blockIdx.x * blockDim.x + threadIdx.x;
  int m = blockIdx.y;
  if (e >= E_) return;
  atomicAdd(&cnt[(long long)m * Nn + dst[(long long)m * E_ + e]], 1);
}

// 3-phase wide scan
__global__ void chunkscan_kernel(const int* __restrict__ cnt, int* __restrict__ rowptr,
                                 int* __restrict__ chunktot)
{
  int m = blockIdx.y, ch = blockIdx.x;
  int base = ch * 1024;
  const int* c = cnt + (long long)m * N_;
  int* rp = rowptr + (long long)m * (N_ + 1);
  __shared__ int sums[256];
  int t = threadIdx.x;
  int v[4]; int s = 0;
  #pragma unroll
  for (int k = 0; k < 4; ++k) {
    int i = base + t * 4 + k;
    v[k] = (i < N_) ? c[i] : 0;
    s += v[k];
  }
  sums[t] = s;
  __syncthreads();
  for (int off = 1; off < 256; off <<= 1) {
    int x = (t >= off) ? sums[t - off] : 0;
    __syncthreads();
    sums[t] += x;
    __syncthreads();
  }
  int run = sums[t] - s;
  #pragma unroll
  for (int k = 0; k < 4; ++k) {
    int i = base + t * 4 + k;
    run += v[k];
    if (i < N_) rp[i + 1] = run;
  }
  if (t == 255) chunktot[m * 64 + ch] = sums[255];
}

__global__ void scantot_kernel(int* __restrict__ chunktot, int nch)
{
  int m = threadIdx.x;
  if (m >= M_) return;
  int run = 0;
  for (int ch = 0; ch < nch; ++ch) {
    int v = chunktot[m * 64 + ch];
    chunktot[m * 64 + ch] = run;
    run += v;
  }
}

__global__ void addoff_kernel(int* __restrict__ rowptr, const int* __restrict__ chunktot)
{
  int m = blockIdx.y, ch = blockIdx.x;
  int off = chunktot[m * 64 + ch];
  int t = threadIdx.x;
  int* rp = rowptr + (long long)m * (N_ + 1);
  #pragma unroll
  for (int k = 0; k < 4; ++k) {
    int i = ch * 1024 + t * 4 + k;
    if (i < N_) rp[i + 1] += off;
  }
  if (ch == 0 && t == 0) rp[0] = 0;
}

__global__ void scatter_kernel(const int* __restrict__ dst, const int* __restrict__ rowptr,
                               int* __restrict__ fill, int* __restrict__ col, int Nn)
{
  int e = blockIdx.x * blockDim.x + threadIdx.x;
  int m = blockIdx.y;
  if (e >= E_) return;
  int d = dst[(long long)m * E_ + e];
  int pos = rowptr[(long long)m * (Nn + 1) + d] + atomicAdd(&fill[(long long)m * Nn + d], 1);
  col[(long long)m * E_ + pos] = e;
}

__global__ void sortbucket_kernel(const int* __restrict__ rowptr, int* __restrict__ col, int Nn)
{
  int n = blockIdx.x * blockDim.x + threadIdx.x;
  int m = blockIdx.y;
  if (n >= Nn) return;
  const int* rp = rowptr + (long long)m * (Nn + 1);
  int* c = col + (long long)m * E_;
  int b = rp[n], e = rp[n + 1];
  for (int i = b + 1; i < e; ++i) {
    int v = c[i]; int j = i - 1;
    while (j >= b && c[j] > v) { c[j + 1] = c[j]; --j; }
    c[j + 1] = v;
  }
}

// per-edge attention logit, edge-parallel
__global__ void edge_e_kernel(const int* __restrict__ src, const int* __restrict__ dst,
                              const float* __restrict__ asrc, const float* __restrict__ adst,
                              float* __restrict__ e_edge)
{
  int e = blockIdx.x * blockDim.x + threadIdx.x;
  int m = blockIdx.y;
  if (e >= E_) return;
  long long off = (long long)m * E_ + e;
  float v = asrc[(long long)m * N_ + src[off]] + adst[(long long)m * N_ + dst[off]];
  e_edge[off] = (v >= 0.f) ? v : 0.2f * v;
}

// per-node softmax over its bucket -> alpha + src id in CSR order
__global__ void alpha_kernel(const int* __restrict__ rowptr, const int* __restrict__ col,
                             const int* __restrict__ src, const float* __restrict__ e_edge,
                             float* __restrict__ alpha, int* __restrict__ src_csr)
{
  int n = blockIdx.x * blockDim.x + threadIdx.x;
  int m = blockIdx.y;
  if (n >= N_) return;
  const int* rp = rowptr + (long long)m * (N_ + 1);
  const int* cl = col + (long long)m * E_;
  const int* sr = src + (long long)m * E_;
  const float* ee = e_edge + (long long)m * E_;
  float* al = alpha + (long long)m * E_;
  int* sc = src_csr + (long long)m * E_;
  int b = rp[n], en = rp[n + 1];
  if (b == en) return;
  float emax = -INFINITY;
  for (int j = b; j < en; ++j) emax = fmaxf(emax, ee[cl[j]]);
  float den = 0.f;
  for (int j = b; j < en; ++j) {
    int eid = cl[j];
    float ez = expf(ee[eid] - emax);
    den += ez;
    al[j] = ez;
    sc[j] = sr[eid];
  }
  float inv = 1.f / (den + 1e-16f);
  for (int j = b; j < en; ++j) al[j] *= inv;
}

// heavy gather: out1[d] = sum_j alpha[j] * xs[src_csr[j]]; 2 dst per block
__global__ void prop2_kernel(const float* __restrict__ xs, const int* __restrict__ rowptr,
                             const float* __restrict__ alpha, const int* __restrict__ src_csr,
                             float* __restrict__ out)
{
  int d = blockIdx.x * 2 + (threadIdx.x >> 7);
  int m = blockIdx.y;
  int c = threadIdx.x & 127;
  if (d >= N_) return;
  const int* rp = rowptr + (long long)m * (N_ + 1);
  const float* al = alpha + (long long)m * E_;
  const int* sc = src_csr + (long long)m * E_;
  const float* xsm = xs + (long long)m * N_ * 128;
  int b = rp[d], en = rp[d + 1];
  float acc = 0.f;
  int j = b;
  for (; j + 3 < en; j += 4) {
    float a0 = al[j], a1 = al[j + 1], a2 = al[j + 2], a3 = al[j + 3];
    int s0 = sc[j], s1 = sc[j + 1], s2 = sc[j + 2], s3 = sc[j + 3];
    float x0 = xsm[(long long)s0 * 128 + c];
    float x1 = xsm[(long long)s1 * 128 + c];
    float x2 = xsm[(long long)s2 * 128 + c];
    float x3 = xsm[(long long)s3 * 128 + c];
    acc += a0 * x0; acc += a1 * x1; acc += a2 * x2; acc += a3 * x3;
  }
  for (; j < en; ++j)
    acc += al[j] * xsm[(long long)sc[j] * 128 + c];
  out[((long long)m * N_ + d) * 128 + c] = acc;
}

// logits[n, 0..3] = h[n,0..255] @ W2[256,4] + b2
__global__ void gate_logits_kernel(const float* __restrict__ h, const float* __restrict__ W2,
                                   const float* __restrict__ b2, float* __restrict__ logits, int Nn)
{
  int w = blockIdx.x * (blockDim.x >> 6) + (threadIdx.x >> 6);
  int lane = threadIdx.x & 63;
  if (w >= Nn) return;
  const float* hr = h + (long long)w * 256;
  float a0 = 0.f, a1 = 0.f, a2 = 0.f, a3 = 0.f;
  for (int j = lane; j < 256; j += 64) {
    float hv = hr[j];
    a0 += hv * W2[j * 4 + 0];
    a1 += hv * W2[j * 4 + 1];
    a2 += hv * W2[j * 4 + 2];
    a3 += hv * W2[j * 4 + 3];
  }
  #pragma unroll
  for (int off = 32; off > 0; off >>= 1) {
    a0 += __shfl_down(a0, off);
    a1 += __shfl_down(a1, off);
    a2 += __shfl_down(a2, off);
    a3 += __shfl_down(a3, off);
  }
  if (lane == 0) {
    long long o = (long long)w * 4;
    logits[o + 0] = a0 + b2[0];
    logits[o + 1] = a1 + b2[1];
    logits[o + 2] = a2 + b2[2];
    logits[o + 3] = a3 + b2[3];
  }
}

// softmax + recept.T + top-2 (ties: lower index) -> wsel[M,N]
__global__ void topk_kernel(const float* __restrict__ logits, const float* __restrict__ recept,
                            float* __restrict__ wsel, int Nn)
{
  int n = blockIdx.x * blockDim.x + threadIdx.x;
  if (n >= Nn) return;
  float l[4];
  #pragma unroll
  for (int m = 0; m < 4; ++m) l[m] = logits[(long long)n * 4 + m];
  float mx = fmaxf(fmaxf(l[0], l[1]), fmaxf(l[2], l[3]));
  float e[4], s = 0.f;
  #pragma unroll
  for (int m = 0; m < 4; ++m) { e[m] = expf(l[m] - mx); s += e[m]; }
  float sc[4];
  #pragma unroll
  for (int m = 0; m < 4; ++m) sc[m] = e[m] / s + recept[(long long)m * Nn + n];
  int i0 = 0; float v0 = sc[0];
  #pragma unroll
  for (int m = 1; m < 4; ++m) if (sc[m] > v0) { v0 = sc[m]; i0 = m; }
  int i1 = -1; float v1 = -INFINITY;
  #pragma unroll
  for (int m = 0; m < 4; ++m) { if (m == i0) continue; if (sc[m] > v1) { v1 = sc[m]; i1 = m; } }
  float ts = v0 + v1;
  float w0 = v0 / ts, w1 = v1 / ts;
  #pragma unroll
  for (int m = 0; m < 4; ++m)
    wsel[(long long)m * Nn + n] = (m == i0) ? w0 : ((m == i1) ? w1 : 0.f);
}

// compaction + record packed position per (m,n)
__global__ void compact_kernel(const float* __restrict__ wsel, int* __restrict__ idx,
                               int* __restrict__ posmn, int* __restrict__ cnts, int Nn)
{
  int n = blockIdx.x * blockDim.x + threadIdx.x;
  if (n >= Nn) return;
  #pragma unroll
  for (int m = 0; m < 4; ++m) {
    if (wsel[(long long)m * Nn + n] != 0.f) {
      int p = atomicAdd(&cnts[m], 1);
      idx[(long long)m * Nn + p] = n;
      posmn[(long long)m * Nn + n] = p;
    }
  }
}

__global__ void prefix4_kernel(const int* __restrict__ cnts, int* __restrict__ off)
{
  if (threadIdx.x == 0) {
    int r = 0;
    #pragma unroll
    for (int m = 0; m < 4; ++m) { off[m] = r; r += cnts[m]; }
  }
}

// final[n] = sum_m wsel[m,n] * outp[(expoff[m]+posmn[m,n])*128 + c]
__global__ void combine_kernel(const float* __restrict__ outp, const float* __restrict__ wsel,
                               const int* __restrict__ posmn, const int* __restrict__ expoff,
                               float* __restrict__ fin)
{
  long long i = (long long)blockIdx.x * blockDim.x + threadIdx.x;
  if (i >= (long long)N_ * 32) return;
  int n = (int)(i >> 5);
  int c4 = (int)(i & 31) * 4;
  float4 acc = make_float4(0.f, 0.f, 0.f, 0.f);
  #pragma unroll
  for (int m = 0; m < 4; ++m) {
    float w = wsel[(long long)m * N_ + n];
    if (w != 0.f) {
      int p = expoff[m] + posmn[(long long)m * N_ + n];
      float4 v = *(const float4*)(outp + (long long)p * 128 + c4);
      acc.x += w * v.x; acc.y += w * v.y; acc.z += w * v.z; acc.w += w * v.w;
    }
  }
  *(float4*)(fin + (long long)n * 128 + c4) = acc;
}

extern "C" void kernel_launch(void* const* d_in, const int* in_sizes, int n_in,
                              void* d_out, int out_size, void* d_ws, size_t ws_size,
                              hipStream_t stream) {
  const float* x_src   = (const float*)d_in[0];
  const float* x_dst   = (const float*)d_in[1];
  const int*   src_idx = (const int*)d_in[2];
  const int*   dst_idx = (const int*)d_in[3];
  const float* proj_Ws = (const float*)d_in[4];
  const float* proj_bs = (const float*)d_in[5];
  const float* projd_W = (const float*)d_in[6];
  const float* projd_b = (const float*)d_in[7];
  const float* lin_src = (const float*)d_in[8];
  const float* lin_dst = (const float*)d_in[9];
  const float* gm_W1   = (const float*)d_in[10];
  const float* gm_b1   = (const float*)d_in[11];
  const float* gm_W2   = (const float*)d_in[12];
  const float* gm_b2   = (const float*)d_in[13];
  const float* gate_W1 = (const float*)d_in[14];
  const float* gate_b1 = (const float*)d_in[15];
  const float* gate_W2 = (const float*)d_in[16];
  const float* gate_b2 = (const float*)d_in[17];
  const float* exp_W1  = (const float*)d_in[18];
  const float* exp_b1  = (const float*)d_in[19];
  const float* exp_W2  = (const float*)d_in[20];
  const float* exp_b2  = (const float*)d_in[21];
  float* final_out = (float*)d_out;

  float* ws = (float*)d_ws;
  float* bufA   = ws;                        // [M,N,128]: xs -> h1 -> gate-h -> packed expert-h
  float* bufB   = ws + 25600000LL;           // [M,N,128]: out1 ; later packed expert-out
  float* xd     = ws + 51200000LL;           // [N,128]
  float* asrc   = ws + 57600000LL;           // [M,N]
  float* adst   = ws + 57800000LL;           // [M,N]
  float* recept = ws + 58000000LL;           // [M,N]
  float* wsel   = ws + 58200000LL;           // [M,N]
  float* logits = ws + 58400000LL;           // [N,4]
  float* e_edge = ws + 58600000LL;           // [M,E]
  float* alpha  = ws + 60200000LL;           // [M,E]
  float* xdW1   = ws + 61800000LL;           // [N,128]
  float* zbuf   = ws + 68200000LL;           // [128] zeros
  int*   ibase  = (int*)(ws + 68300000LL);
  int*   rowptr = ibase;                     // [M,(N+1)]
  int*   col    = ibase + 200004;            // [M,E]
  int*   cnt    = ibase + 1800004;           // [M,N]
  int*   expidx = cnt;                       // reuse after CSR build
  int*   expcnt = ibase + 2000004;           // [4]
  int*   src_csr= ibase + 2000008;           // [M,E]
  int*   chunktot = ibase + 3600008;         // [M,64]
  int*   expoff = ibase + 3600264;           // [4]
  int*   posmn  = ibase + 3600268;           // [M,N]

  const long long NC = (long long)N_ * C_;
  const int RB = (N_ + 63) / 64;             // 782 row blocks
  const int NCH = (N_ + 1023) / 1024;        // 49

  // ---- CSR build ----
  hipMemsetAsync(cnt, 0, (size_t)M_ * N_ * sizeof(int), stream);
  hipMemsetAsync(zbuf, 0, 128 * sizeof(float), stream);
  count_kernel<<<dim3((E_ + 255) / 256, M_), 256, 0, stream>>>(dst_idx, cnt, N_);
  chunkscan_kernel<<<dim3(NCH, M_), 256, 0, stream>>>(cnt, rowptr, chunktot);
  scantot_kernel<<<1, 64, 0, stream>>>(chunktot, NCH);
  addoff_kernel<<<dim3(NCH, M_), 256, 0, stream>>>(rowptr, chunktot);
  hipMemsetAsync(cnt, 0, (size_t)M_ * N_ * sizeof(int), stream);
  scatter_kernel<<<dim3((E_ + 255) / 256, M_), 256, 0, stream>>>(dst_idx, rowptr, cnt, col, N_);
  sortbucket_kernel<<<dim3((N_ + 255) / 256, M_), 256, 0, stream>>>(rowptr, col, N_);

  // ---- xd = x_dst @ projd_W + b ----
  gemm15<0, 0, 0><<<dim3(RB, 1, 1), 256, 0, stream>>>(
      x_dst, nullptr, projd_W, projd_b, xd, nullptr, nullptr, nullptr, nullptr,
      nullptr, nullptr, N_, IN_, C_, 0, 0, 0, 0, 0);
  attn_logit_kernel<<<dim3((N_ + 3) / 4, M_), 256, 0, stream>>>(xd, lin_dst, adst, N_);

  // ---- xdW1 = xd @ gm_W1 (zero bias) ----
  gemm15<0, 0, 0><<<dim3(RB, 1, 1), 256, 0, stream>>>(
      xd, nullptr, gm_W1, zbuf, xdW1, nullptr, nullptr, nullptr, nullptr,
      nullptr, nullptr, N_, C_, C_, 0, 0, 0, 0, 0);

  // ---- xs = per-type projection (batched) + fused a_src row-dot ----
  gemm15<0, 10, 0><<<dim3(RB, M_, 1), 256, 0, stream>>>(
      x_src, nullptr, proj_Ws, proj_bs, bufA, nullptr, nullptr, lin_src, nullptr,
      nullptr, asrc, N_, IN_, C_, NC, (long long)IN_ * C_, C_, NC, 0);

  // ---- attention softmax precompute ----
  edge_e_kernel<<<dim3((E_ + 255) / 256, M_), 256, 0, stream>>>(
      src_idx, dst_idx, asrc, adst, e_edge);
  alpha_kernel<<<dim3((N_ + 255) / 256, M_), 256, 0, stream>>>(
      rowptr, col, src_idx, e_edge, alpha, src_csr);

  // ---- propagation (single gather pass) -> out1 in bufB ----
  prop2_kernel<<<dim3((N_ + 1) / 2, M_), 256, 0, stream>>>(bufA, rowptr, alpha, src_csr, bufB);

  // ---- grad-map MLP: h1 = relu(out1@W1 + b1 - xdW1); fused W2 tail -> recept ----
  gemm15<0, 6, 0><<<dim3(RB, M_, 1), 256, 0, stream>>>(
      bufB, nullptr, gm_W1, gm_b1, bufA, nullptr, nullptr, nullptr, xdW1,
      nullptr, nullptr, N_, C_, C_, NC, 0, 0, NC, 0);
  gemm15<0, 5, 0><<<dim3(RB, M_, 1), 256, 0, stream>>>(
      bufA, xd, gm_W2, gm_b2, recept, nullptr, nullptr, nullptr, bufB,
      nullptr, nullptr, N_, C_, C_, NC, 0, 0, NC, 0);

  // ---- gate: h = relu(gate_in @ W1 + b1); feats fused on A-load ----
  gemm15<2, 1, 1><<<dim3(RB, 1, 2), 256, 0, stream>>>(
      bufB, nullptr, gate_W1, gate_b1, bufA, nullptr, nullptr, recept, nullptr,
      nullptr, nullptr, N_, M_ * C_, HID_, 0, 0, 0, 0, NC);
  gate_logits_kernel<<<dim3((N_ + 3) / 4), 256, 0, stream>>>(bufA, gate_W2, gate_b2, logits, N_);
  topk_kernel<<<(N_ + 255) / 256, 256, 0, stream>>>(logits, recept, wsel, N_);

  // ---- top-2 compaction + packed row offsets ----
  hipMemsetAsync(expcnt, 0, 4 * sizeof(int), stream);
  compact_kernel<<<(N_ + 255) / 256, 256, 0, stream>>>(wsel, expidx, posmn, expcnt, N_);
  prefix4_kernel<<<1, 64, 0, stream>>>(expcnt, expoff);

  // ---- experts: batched W1 (packed h in bufA), batched W2 (packed out), combine ----
  gemm15<4, 7, 2><<<dim3(RB, M_, 2), 256, 0, stream>>>(
      bufB, nullptr, exp_W1, exp_b1, bufA, expidx, expcnt, recept, nullptr,
      expoff, nullptr, N_, C_, HID_, NC, (long long)C_ * HID_, HID_, 0, 0);
  gemm15<5, 9, 0><<<dim3(RB, M_, 1), 256, 0, stream>>>(
      bufA, nullptr, exp_W2, exp_b2, bufB, expidx, expcnt, nullptr, nullptr,
      expoff, nullptr, N_, HID_, C_, 0, (long long)HID_ * C_, C_, 0, 0);
  combine_kernel<<<(int)(((long long)N_ * 32 + 255) / 256), 256, 0, stream>>>(
      bufB, wsel, posmn, expoff, final_out);
}

// Round 16
// 1209.024 us; speedup vs baseline: 1.6321x; 1.0322x over previous
//
#include <hip/hip_runtime.h>
#include <hip/hip_bf16.h>
#include <math.h>

#define M_  4
#define N_  50000
#define E_  400000
#define IN_ 128
#define C_  128
#define HID_ 256

// ---------------------------------------------------------------------------
// Tiled f32 GEMM: 64 rows x 128 cols, 256 threads, 4x8 micro, BK=8,
// single LDS buffer, 2 barriers/tile, 8-VGPR register prefetch.
// Bracketed optimum of the tile-space search:
//   R10 8x8@128^2: 12.2 waves/CU cap, VALU 53%   (wave-starved)
//   R11 4x8@64x128: 24 waves/CU, VALU 60%        <-- core kept here
//   R13 6x8@96x128: VALU 53%                     (LDS-instr heavy)
//   R14 BK=16: bank conflicts 3x, occ 31%
// Proven regressions kept reverted: R3 launch_bounds(256,4) acc spill;
// R6 BK=32 staging spill; R9 LDS dbuf VGPR bloat; R12 A-direct-from-global.
// grid = (ceil(R/64), MB, NC/128)
// AMODE 0: A[b*aBatch + r*K + k]
// AMODE 2: A[(k>>7)*strideM + r*128 + (k&127)]      (gate_in view of [M][N][C])
// AMODE 4: batched gather: row=idx[b*N_+r], Reff=cnts[b], AS[b*N_+row]
// AMODE 5: batched packed:  row=roff[b]+r,  Reff=cnts[b]
// ASCALE 0: none  1: relu(AS[(k>>7)*N_+r]*a)  2: relu(AS[row]*a) (AMODE 4)
// EPI 0: store  1: relu-store
// EPI 5: fused grad-map tail -> recept[b*N_+r]
// EPI 6: relu(acc + bias - sub[r*128+c])            (gm_W1: out1@W1 - xd@W1)
// EPI 7: Cmat[(roff[b]+r)*NC+c] = relu(acc+bias)    (batched packed h)
// EPI 9: Cmat[(roff[b]+r)*128+c] = acc+bias         (batched packed out)
// EPI 10: store + fused row-dot: aux[b*N_+r] = (acc+bias) . AS[b*128+..]
// ---------------------------------------------------------------------------
template<int AMODE, int EPI, int ASCALE>
__global__ void __launch_bounds__(256) gemm16(
    const float* A, const float* A2, const float* __restrict__ B,
    const float* __restrict__ bias, float* Cmat,
    const int* __restrict__ idx, const int* __restrict__ cnts,
    const float* __restrict__ AS, const float* __restrict__ fdbuf,
    const int* __restrict__ roff, float* aux,
    int R, int K, int NC,
    long long aBatch, long long bBatch, int biasBatch, long long cBatch,
    long long strideM)
{
  __shared__ float As[8][64];
  __shared__ float Bs[8][128];
  __shared__ float red[(EPI == 5 || EPI == 10) ? 64 * 17 : 1];

  const int tid = threadIdx.x;
  const int b = blockIdx.y;
  const int Reff = (AMODE == 4 || AMODE == 5) ? cnts[b] : (cnts ? cnts[0] : R);
  const int rb = blockIdx.x * 64;
  if (rb >= Reff) return;
  const int cb = blockIdx.z * 128;

  const float* Ab = (AMODE == 2) ? A : (A + (long long)b * aBatch);
  const float* Bb = B + (long long)b * bBatch + cb;
  const float* biasb = bias + (long long)b * biasBatch + cb;

  // A loader: first 128 threads, 64 rows x 8 k, one float4 each
  const int ar = tid >> 1;            // 0..63 (tid<128)
  const int ak = (tid & 1) * 4;       // 0 or 4
  const int r_a = rb + ar;
  const bool a_ok = (tid < 128) && (r_a < Reff);
  long long a_row = 0;
  float a_rs = 0.f;
  if (a_ok) {
    if (AMODE == 4) {
      int orow = idx[(long long)b * N_ + r_a];
      a_row = (long long)orow * K;
      if (ASCALE == 2) a_rs = AS[(long long)b * N_ + orow];
    } else if (AMODE == 5) {
      a_row = (long long)(roff[b] + r_a) * K;
    } else if (AMODE == 2) {
      a_row = (long long)r_a * 128;
    } else {
      a_row = (long long)r_a * K;
    }
  }
  // B loader: all 256 threads, 8 k x 128 cols, one float4 each
  const int bk = tid >> 5;
  const int bc = (tid & 31) * 4;

  const int tx = tid & 15;
  const int ty = tid >> 4;            // 0..15
  const int fr = ty * 4;              // fragment base row

  float acc[4][8];
  #pragma unroll
  for (int i = 0; i < 4; ++i)
    #pragma unroll
    for (int j = 0; j < 8; ++j) acc[i][j] = 0.f;

  const int nt = K >> 3;
  float4 av = make_float4(0.f, 0.f, 0.f, 0.f), bv;

#define LOAD_TILE(k0)                                                          \
  {                                                                            \
    if (a_ok) {                                                                \
      if (AMODE == 2) {                                                        \
        int kk0 = (k0) + ak;                                                   \
        av = *(const float4*)(Ab + (long long)(kk0 >> 7) * strideM + a_row +   \
                              (kk0 & 127));                                    \
        if (ASCALE == 1) {                                                     \
          float rs = AS[(kk0 >> 7) * N_ + r_a];                                \
          av.x = fmaxf(av.x * rs, 0.f); av.y = fmaxf(av.y * rs, 0.f);          \
          av.z = fmaxf(av.z * rs, 0.f); av.w = fmaxf(av.w * rs, 0.f);          \
        }                                                                      \
      } else {                                                                 \
        av = *(const float4*)(Ab + a_row + (k0) + ak);                         \
        if (AMODE == 4 && ASCALE == 2) {                                       \
          av.x = fmaxf(av.x * a_rs, 0.f); av.y = fmaxf(av.y * a_rs, 0.f);      \
          av.z = fmaxf(av.z * a_rs, 0.f); av.w = fmaxf(av.w * a_rs, 0.f);      \
        }                                                                      \
      }                                                                        \
    } else {                                                                   \
      av = make_float4(0.f, 0.f, 0.f, 0.f);                                    \
    }                                                                          \
    bv = *(const float4*)(Bb + (long long)((k0) + bk) * NC + bc);              \
  }

  // stage tile 0
  LOAD_TILE(0)

  for (int t = 0; t < nt; ++t) {
    __syncthreads();   // readers of LDS (tile t-1) done
    if (tid < 128) {
      As[ak + 0][ar] = av.x; As[ak + 1][ar] = av.y;
      As[ak + 2][ar] = av.z; As[ak + 3][ar] = av.w;
    }
    *(float4*)(&Bs[bk][bc]) = bv;
    __syncthreads();   // tile t visible

    // prefetch tile t+1: loads retire under the FMA block below
    if (t + 1 < nt) LOAD_TILE((t + 1) * 8)

    #pragma unroll
    for (int kk = 0; kk < 8; ++kk) {
      float4 a4 = *(float4*)(&As[kk][fr]);
      float4 blo = *(float4*)(&Bs[kk][tx * 4]);
      float4 bhi = *(float4*)(&Bs[kk][64 + tx * 4]);
      float a_[4] = {a4.x, a4.y, a4.z, a4.w};
      float b8[8] = {blo.x, blo.y, blo.z, blo.w, bhi.x, bhi.y, bhi.z, bhi.w};
      #pragma unroll
      for (int i = 0; i < 4; ++i)
        #pragma unroll
        for (int j = 0; j < 8; ++j)
          acc[i][j] += a_[i] * b8[j];
    }
  }
#undef LOAD_TILE

  if (EPI == 5) {
    // fused: mo = sigmoid(acc+bias); gd = mean_c(mo * (out1 - xd)); recept
    #pragma unroll
    for (int i = 0; i < 4; ++i) {
      const int r_local = fr + i;
      const int r = rb + r_local;
      if (r < Reff) {
        const float* fdrow = fdbuf + (long long)b * cBatch + (long long)r * 128;
        const float* xdrow = A2 + (long long)r * 128;
        float4 flo = *(const float4*)(fdrow + tx * 4);
        float4 fhi = *(const float4*)(fdrow + 64 + tx * 4);
        float4 xlo = *(const float4*)(xdrow + tx * 4);
        float4 xhi = *(const float4*)(xdrow + 64 + tx * 4);
        float fd8[8] = {flo.x - xlo.x, flo.y - xlo.y, flo.z - xlo.z, flo.w - xlo.w,
                        fhi.x - xhi.x, fhi.y - xhi.y, fhi.z - xhi.z, fhi.w - xhi.w};
        float p = 0.f;
        #pragma unroll
        for (int j = 0; j < 8; ++j) {
          const int c = (j < 4 ? tx * 4 + j : 64 + tx * 4 + (j - 4));
          float mo = 1.f / (1.f + expf(-(acc[i][j] + biasb[c])));
          p += mo * fd8[j];
        }
        red[r_local * 17 + tx] = p;
      }
    }
    __syncthreads();
    if (tid < 64) {
      const int r = rb + tid;
      if (r < Reff) {
        float s = 0.f;
        #pragma unroll
        for (int t = 0; t < 16; ++t) s += red[tid * 17 + t];
        float gd = s / 128.f;
        Cmat[(long long)b * N_ + r] = gd / (fabsf(gd) + 1e-8f);
      }
    }
    return;
  }

  #pragma unroll
  for (int i = 0; i < 4; ++i) {
    const int r = rb + fr + i;
    if (r >= Reff) continue;
    long long crow;
    if (EPI == 7) crow = (long long)(roff[b] + r) * NC + cb;
    else if (EPI == 9) crow = (long long)(roff[b] + r) * 128 + cb;
    else crow = (long long)b * cBatch + (long long)r * NC + cb;
    const float* subrow = (EPI == 6) ? (fdbuf + (long long)r * 128 + cb) : nullptr;
    float p = 0.f;
    #pragma unroll
    for (int j = 0; j < 8; ++j) {
      const int c = (j < 4 ? tx * 4 + j : 64 + tx * 4 + (j - 4));
      float v = acc[i][j] + biasb[c];
      if (EPI == 6) v = fmaxf(v - subrow[c], 0.f);
      if (EPI == 1 || EPI == 7) v = fmaxf(v, 0.f);
      Cmat[crow + c] = v;
      if (EPI == 10) p += v * AS[(long long)b * 128 + c];
    }
    if (EPI == 10) red[(fr + i) * 17 + tx] = p;
  }
  if (EPI == 10) {
    __syncthreads();
    if (tid < 64) {
      const int r = rb + tid;
      if (r < Reff) {
        float s = 0.f;
        #pragma unroll
        for (int t = 0; t < 16; ++t) s += red[tid * 17 + t];
        aux[(long long)b * N_ + r] = s;
      }
    }
  }
}

// a[m*Nn + n] = dot(X[n], lin[m*128 ..])  (xd/adst only)
__global__ void attn_logit_kernel(const float* __restrict__ X, const float* __restrict__ lin,
                                  float* __restrict__ out, int Nn)
{
  int m = blockIdx.y;
  int w = blockIdx.x * (blockDim.x >> 6) + (threadIdx.x >> 6);
  int lane = threadIdx.x & 63;
  if (w >= Nn) return;
  const float* xr = X + (long long)w * 128;
  const float* lr = lin + m * 128;
  float acc = xr[lane] * lr[lane] + xr[lane + 64] * lr[lane + 64];
  #pragma unroll
  for (int off = 32; off > 0; off >>= 1) acc += __shfl_down(acc, off);
  if (lane == 0) out[(long long)m * Nn + w] = acc;
}

// ---- CSR build ----
__global__ void count_kernel(const int* __restrict__ dst, int* __restrict__ cnt, int Nn)
{
  int e = blockIdx.x * blockDim.x + threadIdx.x;
  int m = blockIdx.y;
  if (e >= E_) return;
  atomicAdd(&cnt[(long long)m * Nn + dst[(long long)m * E_ + e]], 1);
}

// 3-phase wide scan
__global__ void chunkscan_kernel(const int* __restrict__ cnt, int* __restrict__ rowptr,
                                 int* __restrict__ chunktot)
{
  int m = blockIdx.y, ch = blockIdx.x;
  int base = ch * 1024;
  const int* c = cnt + (long long)m * N_;
  int* rp = rowptr + (long long)m * (N_ + 1);
  __shared__ int sums[256];
  int t = threadIdx.x;
  int v[4]; int s = 0;
  #pragma unroll
  for (int k = 0; k < 4; ++k) {
    int i = base + t * 4 + k;
    v[k] = (i < N_) ? c[i] : 0;
    s += v[k];
  }
  sums[t] = s;
  __syncthreads();
  for (int off = 1; off < 256; off <<= 1) {
    int x = (t >= off) ? sums[t - off] : 0;
    __syncthreads();
    sums[t] += x;
    __syncthreads();
  }
  int run = sums[t] - s;
  #pragma unroll
  for (int k = 0; k < 4; ++k) {
    int i = base + t * 4 + k;
    run += v[k];
    if (i < N_) rp[i + 1] = run;
  }
  if (t == 255) chunktot[m * 64 + ch] = sums[255];
}

__global__ void scantot_kernel(int* __restrict__ chunktot, int nch)
{
  int m = threadIdx.x;
  if (m >= M_) return;
  int run = 0;
  for (int ch = 0; ch < nch; ++ch) {
    int v = chunktot[m * 64 + ch];
    chunktot[m * 64 + ch] = run;
    run += v;
  }
}

__global__ void addoff_kernel(int* __restrict__ rowptr, const int* __restrict__ chunktot)
{
  int m = blockIdx.y, ch = blockIdx.x;
  int off = chunktot[m * 64 + ch];
  int t = threadIdx.x;
  int* rp = rowptr + (long long)m * (N_ + 1);
  #pragma unroll
  for (int k = 0; k < 4; ++k) {
    int i = ch * 1024 + t * 4 + k;
    if (i < N_) rp[i + 1] += off;
  }
  if (ch == 0 && t == 0) rp[0] = 0;
}

__global__ void scatter_kernel(const int* __restrict__ dst, const int* __restrict__ rowptr,
                               int* __restrict__ fill, int* __restrict__ col, int Nn)
{
  int e = blockIdx.x * blockDim.x + threadIdx.x;
  int m = blockIdx.y;
  if (e >= E_) return;
  int d = dst[(long long)m * E_ + e];
  int pos = rowptr[(long long)m * (Nn + 1) + d] + atomicAdd(&fill[(long long)m * Nn + d], 1);
  col[(long long)m * E_ + pos] = e;
}

__global__ void sortbucket_kernel(const int* __restrict__ rowptr, int* __restrict__ col, int Nn)
{
  int n = blockIdx.x * blockDim.x + threadIdx.x;
  int m = blockIdx.y;
  if (n >= Nn) return;
  const int* rp = rowptr + (long long)m * (Nn + 1);
  int* c = col + (long long)m * E_;
  int b = rp[n], e = rp[n + 1];
  for (int i = b + 1; i < e; ++i) {
    int v = c[i]; int j = i - 1;
    while (j >= b && c[j] > v) { c[j + 1] = c[j]; --j; }
    c[j + 1] = v;
  }
}

// per-node softmax over its bucket -> alpha + src id in CSR order
// (edge logit e = leaky(asrc[src]+adst[n]) computed inline; edge_e kernel and
//  the 12.8MB e_edge round-trip removed -- asrc/adst are L2-resident)
__global__ void alpha_kernel(const int* __restrict__ rowptr, const int* __restrict__ col,
                             const int* __restrict__ src, const float* __restrict__ asrc,
                             const float* __restrict__ adst,
                             float* __restrict__ alpha, int* __restrict__ src_csr)
{
  int n = blockIdx.x * blockDim.x + threadIdx.x;
  int m = blockIdx.y;
  if (n >= N_) return;
  const int* rp = rowptr + (long long)m * (N_ + 1);
  const int* cl = col + (long long)m * E_;
  const int* sr = src + (long long)m * E_;
  const float* as_ = asrc + (long long)m * N_;
  float* al = alpha + (long long)m * E_;
  int* sc = src_csr + (long long)m * E_;
  int b = rp[n], en = rp[n + 1];
  if (b == en) return;
  float ad = adst[(long long)m * N_ + n];
  float emax = -INFINITY;
  for (int j = b; j < en; ++j) {
    int s = sr[cl[j]];
    sc[j] = s;
    float e = as_[s] + ad;
    e = (e >= 0.f) ? e : 0.2f * e;
    al[j] = e;                      // stash raw logit
    emax = fmaxf(emax, e);
  }
  float den = 0.f;
  for (int j = b; j < en; ++j) {
    float ez = expf(al[j] - emax);
    den += ez;
    al[j] = ez;
  }
  float inv = 1.f / (den + 1e-16f);
  for (int j = b; j < en; ++j) al[j] *= inv;
}

// heavy gather: out1[d] = sum_j alpha[j] * xs[src_csr[j]]; 2 dst per block
__global__ void prop2_kernel(const float* __restrict__ xs, const int* __restrict__ rowptr,
                             const float* __restrict__ alpha, const int* __restrict__ src_csr,
                             float* __restrict__ out)
{
  int d = blockIdx.x * 2 + (threadIdx.x >> 7);
  int m = blockIdx.y;
  int c = threadIdx.x & 127;
  if (d >= N_) return;
  const int* rp = rowptr + (long long)m * (N_ + 1);
  const float* al = alpha + (long long)m * E_;
  const int* sc = src_csr + (long long)m * E_;
  const float* xsm = xs + (long long)m * N_ * 128;
  int b = rp[d], en = rp[d + 1];
  float acc = 0.f;
  int j = b;
  for (; j + 3 < en; j += 4) {
    float a0 = al[j], a1 = al[j + 1], a2 = al[j + 2], a3 = al[j + 3];
    int s0 = sc[j], s1 = sc[j + 1], s2 = sc[j + 2], s3 = sc[j + 3];
    float x0 = xsm[(long long)s0 * 128 + c];
    float x1 = xsm[(long long)s1 * 128 + c];
    float x2 = xsm[(long long)s2 * 128 + c];
    float x3 = xsm[(long long)s3 * 128 + c];
    acc += a0 * x0; acc += a1 * x1; acc += a2 * x2; acc += a3 * x3;
  }
  for (; j < en; ++j)
    acc += al[j] * xsm[(long long)sc[j] * 128 + c];
  out[((long long)m * N_ + d) * 128 + c] = acc;
}

// logits[n, 0..3] = h[n,0..255] @ W2[256,4] + b2
__global__ void gate_logits_kernel(const float* __restrict__ h, const float* __restrict__ W2,
                                   const float* __restrict__ b2, float* __restrict__ logits, int Nn)
{
  int w = blockIdx.x * (blockDim.x >> 6) + (threadIdx.x >> 6);
  int lane = threadIdx.x & 63;
  if (w >= Nn) return;
  const float* hr = h + (long long)w * 256;
  float a0 = 0.f, a1 = 0.f, a2 = 0.f, a3 = 0.f;
  for (int j = lane; j < 256; j += 64) {
    float hv = hr[j];
    a0 += hv * W2[j * 4 + 0];
    a1 += hv * W2[j * 4 + 1];
    a2 += hv * W2[j * 4 + 2];
    a3 += hv * W2[j * 4 + 3];
  }
  #pragma unroll
  for (int off = 32; off > 0; off >>= 1) {
    a0 += __shfl_down(a0, off);
    a1 += __shfl_down(a1, off);
    a2 += __shfl_down(a2, off);
    a3 += __shfl_down(a3, off);
  }
  if (lane == 0) {
    long long o = (long long)w * 4;
    logits[o + 0] = a0 + b2[0];
    logits[o + 1] = a1 + b2[1];
    logits[o + 2] = a2 + b2[2];
    logits[o + 3] = a3 + b2[3];
  }
}

// softmax + recept.T + top-2 (ties: lower index) -> wsel[M,N]
__global__ void topk_kernel(const float* __restrict__ logits, const float* __restrict__ recept,
                            float* __restrict__ wsel, int Nn)
{
  int n = blockIdx.x * blockDim.x + threadIdx.x;
  if (n >= Nn) return;
  float l[4];
  #pragma unroll
  for (int m = 0; m < 4; ++m) l[m] = logits[(long long)n * 4 + m];
  float mx = fmaxf(fmaxf(l[0], l[1]), fmaxf(l[2], l[3]));
  float e[4], s = 0.f;
  #pragma unroll
  for (int m = 0; m < 4; ++m) { e[m] = expf(l[m] - mx); s += e[m]; }
  float sc[4];
  #pragma unroll
  for (int m = 0; m < 4; ++m) sc[m] = e[m] / s + recept[(long long)m * Nn + n];
  int i0 = 0; float v0 = sc[0];
  #pragma unroll
  for (int m = 1; m < 4; ++m) if (sc[m] > v0) { v0 = sc[m]; i0 = m; }
  int i1 = -1; float v1 = -INFINITY;
  #pragma unroll
  for (int m = 0; m < 4; ++m) { if (m == i0) continue; if (sc[m] > v1) { v1 = sc[m]; i1 = m; } }
  float ts = v0 + v1;
  float w0 = v0 / ts, w1 = v1 / ts;
  #pragma unroll
  for (int m = 0; m < 4; ++m)
    wsel[(long long)m * Nn + n] = (m == i0) ? w0 : ((m == i1) ? w1 : 0.f);
}

// compaction + record packed position per (m,n)
__global__ void compact_kernel(const float* __restrict__ wsel, int* __restrict__ idx,
                               int* __restrict__ posmn, int* __restrict__ cnts, int Nn)
{
  int n = blockIdx.x * blockDim.x + threadIdx.x;
  if (n >= Nn) return;
  #pragma unroll
  for (int m = 0; m < 4; ++m) {
    if (wsel[(long long)m * Nn + n] != 0.f) {
      int p = atomicAdd(&cnts[m], 1);
      idx[(long long)m * Nn + p] = n;
      posmn[(long long)m * Nn + n] = p;
    }
  }
}

__global__ void prefix4_kernel(const int* __restrict__ cnts, int* __restrict__ off)
{
  if (threadIdx.x == 0) {
    int r = 0;
    #pragma unroll
    for (int m = 0; m < 4; ++m) { off[m] = r; r += cnts[m]; }
  }
}

// final[n] = sum_m wsel[m,n] * outp[(expoff[m]+posmn[m,n])*128 + c]
__global__ void combine_kernel(const float* __restrict__ outp, const float* __restrict__ wsel,
                               const int* __restrict__ posmn, const int* __restrict__ expoff,
                               float* __restrict__ fin)
{
  long long i = (long long)blockIdx.x * blockDim.x + threadIdx.x;
  if (i >= (long long)N_ * 32) return;
  int n = (int)(i >> 5);
  int c4 = (int)(i & 31) * 4;
  float4 acc = make_float4(0.f, 0.f, 0.f, 0.f);
  #pragma unroll
  for (int m = 0; m < 4; ++m) {
    float w = wsel[(long long)m * N_ + n];
    if (w != 0.f) {
      int p = expoff[m] + posmn[(long long)m * N_ + n];
      float4 v = *(const float4*)(outp + (long long)p * 128 + c4);
      acc.x += w * v.x; acc.y += w * v.y; acc.z += w * v.z; acc.w += w * v.w;
    }
  }
  *(float4*)(fin + (long long)n * 128 + c4) = acc;
}

extern "C" void kernel_launch(void* const* d_in, const int* in_sizes, int n_in,
                              void* d_out, int out_size, void* d_ws, size_t ws_size,
                              hipStream_t stream) {
  const float* x_src   = (const float*)d_in[0];
  const float* x_dst   = (const float*)d_in[1];
  const int*   src_idx = (const int*)d_in[2];
  const int*   dst_idx = (const int*)d_in[3];
  const float* proj_Ws = (const float*)d_in[4];
  const float* proj_bs = (const float*)d_in[5];
  const float* projd_W = (const float*)d_in[6];
  const float* projd_b = (const float*)d_in[7];
  const float* lin_src = (const float*)d_in[8];
  const float* lin_dst = (const float*)d_in[9];
  const float* gm_W1   = (const float*)d_in[10];
  const float* gm_b1   = (const float*)d_in[11];
  const float* gm_W2   = (const float*)d_in[12];
  const float* gm_b2   = (const float*)d_in[13];
  const float* gate_W1 = (const float*)d_in[14];
  const float* gate_b1 = (const float*)d_in[15];
  const float* gate_W2 = (const float*)d_in[16];
  const float* gate_b2 = (const float*)d_in[17];
  const float* exp_W1  = (const float*)d_in[18];
  const float* exp_b1  = (const float*)d_in[19];
  const float* exp_W2  = (const float*)d_in[20];
  const float* exp_b2  = (const float*)d_in[21];
  float* final_out = (float*)d_out;

  float* ws = (float*)d_ws;
  float* bufA   = ws;                        // [M,N,128]: xs -> h1 -> gate-h -> packed expert-h
  float* bufB   = ws + 25600000LL;           // [M,N,128]: out1 ; later packed expert-out
  float* xd     = ws + 51200000LL;           // [N,128]
  float* asrc   = ws + 57600000LL;           // [M,N]
  float* adst   = ws + 57800000LL;           // [M,N]
  float* recept = ws + 58000000LL;           // [M,N]
  float* wsel   = ws + 58200000LL;           // [M,N]
  float* logits = ws + 58400000LL;           // [N,4]
  float* alpha  = ws + 58600000LL;           // [M,E]
  float* xdW1   = ws + 60200000LL;           // [N,128]
  float* zbuf   = ws + 66600000LL;           // [128] zeros
  int*   ibase  = (int*)(ws + 66700000LL);
  int*   rowptr = ibase;                     // [M,(N+1)]
  int*   col    = ibase + 200004;            // [M,E]
  int*   cnt    = ibase + 1800004;           // [M,N]
  int*   expidx = cnt;                       // reuse after CSR build
  int*   expcnt = ibase + 2000004;           // [4]
  int*   src_csr= ibase + 2000008;           // [M,E]
  int*   chunktot = ibase + 3600008;         // [M,64]
  int*   expoff = ibase + 3600264;           // [4]
  int*   posmn  = ibase + 3600268;           // [M,N]

  const long long NC = (long long)N_ * C_;
  const int RB = (N_ + 63) / 64;             // 782 row blocks
  const int NCH = (N_ + 1023) / 1024;        // 49

  // ---- CSR build ----
  hipMemsetAsync(cnt, 0, (size_t)M_ * N_ * sizeof(int), stream);
  hipMemsetAsync(zbuf, 0, 128 * sizeof(float), stream);
  count_kernel<<<dim3((E_ + 255) / 256, M_), 256, 0, stream>>>(dst_idx, cnt, N_);
  chunkscan_kernel<<<dim3(NCH, M_), 256, 0, stream>>>(cnt, rowptr, chunktot);
  scantot_kernel<<<1, 64, 0, stream>>>(chunktot, NCH);
  addoff_kernel<<<dim3(NCH, M_), 256, 0, stream>>>(rowptr, chunktot);
  hipMemsetAsync(cnt, 0, (size_t)M_ * N_ * sizeof(int), stream);
  scatter_kernel<<<dim3((E_ + 255) / 256, M_), 256, 0, stream>>>(dst_idx, rowptr, cnt, col, N_);
  sortbucket_kernel<<<dim3((N_ + 255) / 256, M_), 256, 0, stream>>>(rowptr, col, N_);

  // ---- xd = x_dst @ projd_W + b ----
  gemm16<0, 0, 0><<<dim3(RB, 1, 1), 256, 0, stream>>>(
      x_dst, nullptr, projd_W, projd_b, xd, nullptr, nullptr, nullptr, nullptr,
      nullptr, nullptr, N_, IN_, C_, 0, 0, 0, 0, 0);
  attn_logit_kernel<<<dim3((N_ + 3) / 4, M_), 256, 0, stream>>>(xd, lin_dst, adst, N_);

  // ---- xdW1 = xd @ gm_W1 (zero bias) ----
  gemm16<0, 0, 0><<<dim3(RB, 1, 1), 256, 0, stream>>>(
      xd, nullptr, gm_W1, zbuf, xdW1, nullptr, nullptr, nullptr, nullptr,
      nullptr, nullptr, N_, C_, C_, 0, 0, 0, 0, 0);

  // ---- xs = per-type projection (batched) + fused a_src row-dot ----
  gemm16<0, 10, 0><<<dim3(RB, M_, 1), 256, 0, stream>>>(
      x_src, nullptr, proj_Ws, proj_bs, bufA, nullptr, nullptr, lin_src, nullptr,
      nullptr, asrc, N_, IN_, C_, NC, (long long)IN_ * C_, C_, NC, 0);

  // ---- attention softmax (edge logit computed inline) ----
  alpha_kernel<<<dim3((N_ + 255) / 256, M_), 256, 0, stream>>>(
      rowptr, col, src_idx, asrc, adst, alpha, src_csr);

  // ---- propagation (single gather pass) -> out1 in bufB ----
  prop2_kernel<<<dim3((N_ + 1) / 2, M_), 256, 0, stream>>>(bufA, rowptr, alpha, src_csr, bufB);

  // ---- grad-map MLP: h1 = relu(out1@W1 + b1 - xdW1); fused W2 tail -> recept ----
  gemm16<0, 6, 0><<<dim3(RB, M_, 1), 256, 0, stream>>>(
      bufB, nullptr, gm_W1, gm_b1, bufA, nullptr, nullptr, nullptr, xdW1,
      nullptr, nullptr, N_, C_, C_, NC, 0, 0, NC, 0);
  gemm16<0, 5, 0><<<dim3(RB, M_, 1), 256, 0, stream>>>(
      bufA, xd, gm_W2, gm_b2, recept, nullptr, nullptr, nullptr, bufB,
      nullptr, nullptr, N_, C_, C_, NC, 0, 0, NC, 0);

  // ---- gate: h = relu(gate_in @ W1 + b1); feats fused on A-load ----
  gemm16<2, 1, 1><<<dim3(RB, 1, 2), 256, 0, stream>>>(
      bufB, nullptr, gate_W1, gate_b1, bufA, nullptr, nullptr, recept, nullptr,
      nullptr, nullptr, N_, M_ * C_, HID_, 0, 0, 0, 0, NC);
  gate_logits_kernel<<<dim3((N_ + 3) / 4), 256, 0, stream>>>(bufA, gate_W2, gate_b2, logits, N_);
  topk_kernel<<<(N_ + 255) / 256, 256, 0, stream>>>(logits, recept, wsel, N_);

  // ---- top-2 compaction + packed row offsets ----
  hipMemsetAsync(expcnt, 0, 4 * sizeof(int), stream);
  compact_kernel<<<(N_ + 255) / 256, 256, 0, stream>>>(wsel, expidx, posmn, expcnt, N_);
  prefix4_kernel<<<1, 64, 0, stream>>>(expcnt, expoff);

  // ---- experts: batched W1 (packed h in bufA), batched W2 (packed out), combine ----
  gemm16<4, 7, 2><<<dim3(RB, M_, 2), 256, 0, stream>>>(
      bufB, nullptr, exp_W1, exp_b1, bufA, expidx, expcnt, recept, nullptr,
      expoff, nullptr, N_, C_, HID_, NC, (long long)C_ * HID_, HID_, 0, 0);
  gemm16<5, 9, 0><<<dim3(RB, M_, 1), 256, 0, stream>>>(
      bufA, nullptr, exp_W2, exp_b2, bufB, expidx, expcnt, nullptr, nullptr,
      expoff, nullptr, N_, HID_, C_, 0, (long long)HID_ * C_, C_, 0, 0);
  combine_kernel<<<(int)(((long long)N_ * 32 + 255) / 256), 256, 0, stream>>>(
      bufB, wsel, posmn, expoff, final_out);
}

// Round 17
// 1186.424 us; speedup vs baseline: 1.6631x; 1.0190x over previous
//
#include <hip/hip_runtime.h>
#include <hip/hip_bf16.h>
#include <math.h>

#define M_  4
#define N_  50000
#define E_  400000
#define IN_ 128
#define C_  128
#define HID_ 256

// ---------------------------------------------------------------------------
// Tiled f32 GEMM: 64 rows x 128 cols, 256 threads, 4x8 micro, BK=8,
// single LDS buffer, 2 barriers/tile, 8-VGPR register prefetch.
// Bracketed optimum of the tile-space search (R10/R11/R13/R14).
// Proven regressions kept reverted: R3 launch_bounds(256,4) acc spill;
// R6 BK=32 staging spill; R9 LDS dbuf VGPR bloat; R12 A-direct-from-global.
// MFMA is closed off by correctness: bf16 cast flips sign(gd) for near-zero
// gd -> recept flips by 2.0 -> absmax blowup.
// grid = (ceil(R/64), MB, NC/128)
// AMODE 0: A[b*aBatch + r*K + k]
// AMODE 2: A[(k>>7)*strideM + r*128 + (k&127)]      (gate_in view of [M][N][C])
// AMODE 4: batched gather: row=idx[b*N_+r], Reff=cnts[b], AS[b*N_+row]
// AMODE 5: batched packed:  row=roff[b]+r,  Reff=cnts[b]
// ASCALE 0: none  1: relu(AS[(k>>7)*N_+r]*a)  2: relu(AS[row]*a) (AMODE 4)
// EPI 0: store  1: relu-store
// EPI 5: fused grad-map tail -> recept[b*N_+r]
// EPI 6: relu(acc + bias - sub[r*128+c])            (gm_W1: out1@W1 - xd@W1)
// EPI 7: Cmat[(roff[b]+r)*NC+c] = relu(acc+bias)    (batched packed h)
// EPI 9: Cmat[(roff[b]+r)*128+c] = acc+bias         (batched packed out)
// EPI 10: store + fused row-dot: aux[b*N_+r] = (acc+bias) . AS[b*128+..]
// EPI 11: store + FOUR fused row-dots: aux[mm*N_+r] = (acc+bias).AS[mm*128+..]
//         (xd projection + all 4 adst logits; kills attn_logit + 102MB re-read)
// ---------------------------------------------------------------------------
template<int AMODE, int EPI, int ASCALE>
__global__ void __launch_bounds__(256) gemm17(
    const float* A, const float* A2, const float* __restrict__ B,
    const float* __restrict__ bias, float* Cmat,
    const int* __restrict__ idx, const int* __restrict__ cnts,
    const float* __restrict__ AS, const float* __restrict__ fdbuf,
    const int* __restrict__ roff, float* aux,
    int R, int K, int NC,
    long long aBatch, long long bBatch, int biasBatch, long long cBatch,
    long long strideM)
{
  __shared__ float As[8][64];
  __shared__ float Bs[8][128];
  __shared__ float red[(EPI == 5 || EPI == 10) ? 64 * 17 : 1];
  __shared__ float4 red4[(EPI == 11) ? 64 * 17 : 1];

  const int tid = threadIdx.x;
  const int b = blockIdx.y;
  const int Reff = (AMODE == 4 || AMODE == 5) ? cnts[b] : (cnts ? cnts[0] : R);
  const int rb = blockIdx.x * 64;
  if (rb >= Reff) return;
  const int cb = blockIdx.z * 128;

  const float* Ab = (AMODE == 2) ? A : (A + (long long)b * aBatch);
  const float* Bb = B + (long long)b * bBatch + cb;
  const float* biasb = bias + (long long)b * biasBatch + cb;

  // A loader: first 128 threads, 64 rows x 8 k, one float4 each
  const int ar = tid >> 1;            // 0..63 (tid<128)
  const int ak = (tid & 1) * 4;       // 0 or 4
  const int r_a = rb + ar;
  const bool a_ok = (tid < 128) && (r_a < Reff);
  long long a_row = 0;
  float a_rs = 0.f;
  if (a_ok) {
    if (AMODE == 4) {
      int orow = idx[(long long)b * N_ + r_a];
      a_row = (long long)orow * K;
      if (ASCALE == 2) a_rs = AS[(long long)b * N_ + orow];
    } else if (AMODE == 5) {
      a_row = (long long)(roff[b] + r_a) * K;
    } else if (AMODE == 2) {
      a_row = (long long)r_a * 128;
    } else {
      a_row = (long long)r_a * K;
    }
  }
  // B loader: all 256 threads, 8 k x 128 cols, one float4 each
  const int bk = tid >> 5;
  const int bc = (tid & 31) * 4;

  const int tx = tid & 15;
  const int ty = tid >> 4;            // 0..15
  const int fr = ty * 4;              // fragment base row

  float acc[4][8];
  #pragma unroll
  for (int i = 0; i < 4; ++i)
    #pragma unroll
    for (int j = 0; j < 8; ++j) acc[i][j] = 0.f;

  const int nt = K >> 3;
  float4 av = make_float4(0.f, 0.f, 0.f, 0.f), bv;

#define LOAD_TILE(k0)                                                          \
  {                                                                            \
    if (a_ok) {                                                                \
      if (AMODE == 2) {                                                        \
        int kk0 = (k0) + ak;                                                   \
        av = *(const float4*)(Ab + (long long)(kk0 >> 7) * strideM + a_row +   \
                              (kk0 & 127));                                    \
        if (ASCALE == 1) {                                                     \
          float rs = AS[(kk0 >> 7) * N_ + r_a];                                \
          av.x = fmaxf(av.x * rs, 0.f); av.y = fmaxf(av.y * rs, 0.f);          \
          av.z = fmaxf(av.z * rs, 0.f); av.w = fmaxf(av.w * rs, 0.f);          \
        }                                                                      \
      } else {                                                                 \
        av = *(const float4*)(Ab + a_row + (k0) + ak);                         \
        if (AMODE == 4 && ASCALE == 2) {                                       \
          av.x = fmaxf(av.x * a_rs, 0.f); av.y = fmaxf(av.y * a_rs, 0.f);      \
          av.z = fmaxf(av.z * a_rs, 0.f); av.w = fmaxf(av.w * a_rs, 0.f);      \
        }                                                                      \
      }                                                                        \
    } else {                                                                   \
      av = make_float4(0.f, 0.f, 0.f, 0.f);                                    \
    }                                                                          \
    bv = *(const float4*)(Bb + (long long)((k0) + bk) * NC + bc);              \
  }

  // stage tile 0
  LOAD_TILE(0)

  for (int t = 0; t < nt; ++t) {
    __syncthreads();   // readers of LDS (tile t-1) done
    if (tid < 128) {
      As[ak + 0][ar] = av.x; As[ak + 1][ar] = av.y;
      As[ak + 2][ar] = av.z; As[ak + 3][ar] = av.w;
    }
    *(float4*)(&Bs[bk][bc]) = bv;
    __syncthreads();   // tile t visible

    // prefetch tile t+1: loads retire under the FMA block below
    if (t + 1 < nt) LOAD_TILE((t + 1) * 8)

    #pragma unroll
    for (int kk = 0; kk < 8; ++kk) {
      float4 a4 = *(float4*)(&As[kk][fr]);
      float4 blo = *(float4*)(&Bs[kk][tx * 4]);
      float4 bhi = *(float4*)(&Bs[kk][64 + tx * 4]);
      float a_[4] = {a4.x, a4.y, a4.z, a4.w};
      float b8[8] = {blo.x, blo.y, blo.z, blo.w, bhi.x, bhi.y, bhi.z, bhi.w};
      #pragma unroll
      for (int i = 0; i < 4; ++i)
        #pragma unroll
        for (int j = 0; j < 8; ++j)
          acc[i][j] += a_[i] * b8[j];
    }
  }
#undef LOAD_TILE

  if (EPI == 5) {
    // fused: mo = sigmoid(acc+bias); gd = mean_c(mo * (out1 - xd)); recept
    #pragma unroll
    for (int i = 0; i < 4; ++i) {
      const int r_local = fr + i;
      const int r = rb + r_local;
      if (r < Reff) {
        const float* fdrow = fdbuf + (long long)b * cBatch + (long long)r * 128;
        const float* xdrow = A2 + (long long)r * 128;
        float4 flo = *(const float4*)(fdrow + tx * 4);
        float4 fhi = *(const float4*)(fdrow + 64 + tx * 4);
        float4 xlo = *(const float4*)(xdrow + tx * 4);
        float4 xhi = *(const float4*)(xdrow + 64 + tx * 4);
        float fd8[8] = {flo.x - xlo.x, flo.y - xlo.y, flo.z - xlo.z, flo.w - xlo.w,
                        fhi.x - xhi.x, fhi.y - xhi.y, fhi.z - xhi.z, fhi.w - xhi.w};
        float p = 0.f;
        #pragma unroll
        for (int j = 0; j < 8; ++j) {
          const int c = (j < 4 ? tx * 4 + j : 64 + tx * 4 + (j - 4));
          float mo = 1.f / (1.f + expf(-(acc[i][j] + biasb[c])));
          p += mo * fd8[j];
        }
        red[r_local * 17 + tx] = p;
      }
    }
    __syncthreads();
    if (tid < 64) {
      const int r = rb + tid;
      if (r < Reff) {
        float s = 0.f;
        #pragma unroll
        for (int t = 0; t < 16; ++t) s += red[tid * 17 + t];
        float gd = s / 128.f;
        Cmat[(long long)b * N_ + r] = gd / (fabsf(gd) + 1e-8f);
      }
    }
    return;
  }

  #pragma unroll
  for (int i = 0; i < 4; ++i) {
    const int r = rb + fr + i;
    if (r >= Reff) continue;
    long long crow;
    if (EPI == 7) crow = (long long)(roff[b] + r) * NC + cb;
    else if (EPI == 9) crow = (long long)(roff[b] + r) * 128 + cb;
    else crow = (long long)b * cBatch + (long long)r * NC + cb;
    const float* subrow = (EPI == 6) ? (fdbuf + (long long)r * 128 + cb) : nullptr;
    float p = 0.f;
    float4 p4 = make_float4(0.f, 0.f, 0.f, 0.f);
    #pragma unroll
    for (int j = 0; j < 8; ++j) {
      const int c = (j < 4 ? tx * 4 + j : 64 + tx * 4 + (j - 4));
      float v = acc[i][j] + biasb[c];
      if (EPI == 6) v = fmaxf(v - subrow[c], 0.f);
      if (EPI == 1 || EPI == 7) v = fmaxf(v, 0.f);
      Cmat[crow + c] = v;
      if (EPI == 10) p += v * AS[(long long)b * 128 + c];
      if (EPI == 11) {
        p4.x += v * AS[0 * 128 + c];
        p4.y += v * AS[1 * 128 + c];
        p4.z += v * AS[2 * 128 + c];
        p4.w += v * AS[3 * 128 + c];
      }
    }
    if (EPI == 10) red[(fr + i) * 17 + tx] = p;
    if (EPI == 11) red4[(fr + i) * 17 + tx] = p4;
  }
  if (EPI == 10) {
    __syncthreads();
    if (tid < 64) {
      const int r = rb + tid;
      if (r < Reff) {
        float s = 0.f;
        #pragma unroll
        for (int t = 0; t < 16; ++t) s += red[tid * 17 + t];
        aux[(long long)b * N_ + r] = s;
      }
    }
  }
  if (EPI == 11) {
    __syncthreads();
    if (tid < 64) {
      const int r = rb + tid;
      if (r < Reff) {
        float4 s = make_float4(0.f, 0.f, 0.f, 0.f);
        #pragma unroll
        for (int t = 0; t < 16; ++t) {
          float4 v = red4[tid * 17 + t];
          s.x += v.x; s.y += v.y; s.z += v.z; s.w += v.w;
        }
        aux[0LL * N_ + r] = s.x;
        aux[1LL * N_ + r] = s.y;
        aux[2LL * N_ + r] = s.z;
        aux[3LL * N_ + r] = s.w;
      }
    }
  }
}

// ---- CSR build ----
__global__ void count_kernel(const int* __restrict__ dst, int* __restrict__ cnt, int Nn)
{
  int e = blockIdx.x * blockDim.x + threadIdx.x;
  int m = blockIdx.y;
  if (e >= E_) return;
  atomicAdd(&cnt[(long long)m * Nn + dst[(long long)m * E_ + e]], 1);
}

// 3-phase wide scan
__global__ void chunkscan_kernel(const int* __restrict__ cnt, int* __restrict__ rowptr,
                                 int* __restrict__ chunktot)
{
  int m = blockIdx.y, ch = blockIdx.x;
  int base = ch * 1024;
  const int* c = cnt + (long long)m * N_;
  int* rp = rowptr + (long long)m * (N_ + 1);
  __shared__ int sums[256];
  int t = threadIdx.x;
  int v[4]; int s = 0;
  #pragma unroll
  for (int k = 0; k < 4; ++k) {
    int i = base + t * 4 + k;
    v[k] = (i < N_) ? c[i] : 0;
    s += v[k];
  }
  sums[t] = s;
  __syncthreads();
  for (int off = 1; off < 256; off <<= 1) {
    int x = (t >= off) ? sums[t - off] : 0;
    __syncthreads();
    sums[t] += x;
    __syncthreads();
  }
  int run = sums[t] - s;
  #pragma unroll
  for (int k = 0; k < 4; ++k) {
    int i = base + t * 4 + k;
    run += v[k];
    if (i < N_) rp[i + 1] = run;
  }
  if (t == 255) chunktot[m * 64 + ch] = sums[255];
}

__global__ void scantot_kernel(int* __restrict__ chunktot, int nch)
{
  int m = threadIdx.x;
  if (m >= M_) return;
  int run = 0;
  for (int ch = 0; ch < nch; ++ch) {
    int v = chunktot[m * 64 + ch];
    chunktot[m * 64 + ch] = run;
    run += v;
  }
}

__global__ void addoff_kernel(int* __restrict__ rowptr, const int* __restrict__ chunktot)
{
  int m = blockIdx.y, ch = blockIdx.x;
  int off = chunktot[m * 64 + ch];
  int t = threadIdx.x;
  int* rp = rowptr + (long long)m * (N_ + 1);
  #pragma unroll
  for (int k = 0; k < 4; ++k) {
    int i = ch * 1024 + t * 4 + k;
    if (i < N_) rp[i + 1] += off;
  }
  if (ch == 0 && t == 0) rp[0] = 0;
}

__global__ void scatter_kernel(const int* __restrict__ dst, const int* __restrict__ rowptr,
                               int* __restrict__ fill, int* __restrict__ col, int Nn)
{
  int e = blockIdx.x * blockDim.x + threadIdx.x;
  int m = blockIdx.y;
  if (e >= E_) return;
  int d = dst[(long long)m * E_ + e];
  int pos = rowptr[(long long)m * (Nn + 1) + d] + atomicAdd(&fill[(long long)m * Nn + d], 1);
  col[(long long)m * E_ + pos] = e;
}

__global__ void sortbucket_kernel(const int* __restrict__ rowptr, int* __restrict__ col, int Nn)
{
  int n = blockIdx.x * blockDim.x + threadIdx.x;
  int m = blockIdx.y;
  if (n >= Nn) return;
  const int* rp = rowptr + (long long)m * (Nn + 1);
  int* c = col + (long long)m * E_;
  int b = rp[n], e = rp[n + 1];
  for (int i = b + 1; i < e; ++i) {
    int v = c[i]; int j = i - 1;
    while (j >= b && c[j] > v) { c[j + 1] = c[j]; --j; }
    c[j + 1] = v;
  }
}

// per-node softmax over its bucket -> alpha + src id in CSR order
// (edge logit computed inline; asrc/adst L2-resident)
__global__ void alpha_kernel(const int* __restrict__ rowptr, const int* __restrict__ col,
                             const int* __restrict__ src, const float* __restrict__ asrc,
                             const float* __restrict__ adst,
                             float* __restrict__ alpha, int* __restrict__ src_csr)
{
  int n = blockIdx.x * blockDim.x + threadIdx.x;
  int m = blockIdx.y;
  if (n >= N_) return;
  const int* rp = rowptr + (long long)m * (N_ + 1);
  const int* cl = col + (long long)m * E_;
  const int* sr = src + (long long)m * E_;
  const float* as_ = asrc + (long long)m * N_;
  float* al = alpha + (long long)m * E_;
  int* sc = src_csr + (long long)m * E_;
  int b = rp[n], en = rp[n + 1];
  if (b == en) return;
  float ad = adst[(long long)m * N_ + n];
  float emax = -INFINITY;
  for (int j = b; j < en; ++j) {
    int s = sr[cl[j]];
    sc[j] = s;
    float e = as_[s] + ad;
    e = (e >= 0.f) ? e : 0.2f * e;
    al[j] = e;
    emax = fmaxf(emax, e);
  }
  float den = 0.f;
  for (int j = b; j < en; ++j) {
    float ez = expf(al[j] - emax);
    den += ez;
    al[j] = ez;
  }
  float inv = 1.f / (den + 1e-16f);
  for (int j = b; j < en; ++j) al[j] *= inv;
}

// heavy gather: out1[d] = sum_j alpha[j] * xs[src_csr[j]]; 2 dst per block
__global__ void prop2_kernel(const float* __restrict__ xs, const int* __restrict__ rowptr,
                             const float* __restrict__ alpha, const int* __restrict__ src_csr,
                             float* __restrict__ out)
{
  int d = blockIdx.x * 2 + (threadIdx.x >> 7);
  int m = blockIdx.y;
  int c = threadIdx.x & 127;
  if (d >= N_) return;
  const int* rp = rowptr + (long long)m * (N_ + 1);
  const float* al = alpha + (long long)m * E_;
  const int* sc = src_csr + (long long)m * E_;
  const float* xsm = xs + (long long)m * N_ * 128;
  int b = rp[d], en = rp[d + 1];
  float acc = 0.f;
  int j = b;
  for (; j + 3 < en; j += 4) {
    float a0 = al[j], a1 = al[j + 1], a2 = al[j + 2], a3 = al[j + 3];
    int s0 = sc[j], s1 = sc[j + 1], s2 = sc[j + 2], s3 = sc[j + 3];
    float x0 = xsm[(long long)s0 * 128 + c];
    float x1 = xsm[(long long)s1 * 128 + c];
    float x2 = xsm[(long long)s2 * 128 + c];
    float x3 = xsm[(long long)s3 * 128 + c];
    acc += a0 * x0; acc += a1 * x1; acc += a2 * x2; acc += a3 * x3;
  }
  for (; j < en; ++j)
    acc += al[j] * xsm[(long long)sc[j] * 128 + c];
  out[((long long)m * N_ + d) * 128 + c] = acc;
}

// logits[n, 0..3] = h[n,0..255] @ W2[256,4] + b2
__global__ void gate_logits_kernel(const float* __restrict__ h, const float* __restrict__ W2,
                                   const float* __restrict__ b2, float* __restrict__ logits, int Nn)
{
  int w = blockIdx.x * (blockDim.x >> 6) + (threadIdx.x >> 6);
  int lane = threadIdx.x & 63;
  if (w >= Nn) return;
  const float* hr = h + (long long)w * 256;
  float a0 = 0.f, a1 = 0.f, a2 = 0.f, a3 = 0.f;
  for (int j = lane; j < 256; j += 64) {
    float hv = hr[j];
    a0 += hv * W2[j * 4 + 0];
    a1 += hv * W2[j * 4 + 1];
    a2 += hv * W2[j * 4 + 2];
    a3 += hv * W2[j * 4 + 3];
  }
  #pragma unroll
  for (int off = 32; off > 0; off >>= 1) {
    a0 += __shfl_down(a0, off);
    a1 += __shfl_down(a1, off);
    a2 += __shfl_down(a2, off);
    a3 += __shfl_down(a3, off);
  }
  if (lane == 0) {
    long long o = (long long)w * 4;
    logits[o + 0] = a0 + b2[0];
    logits[o + 1] = a1 + b2[1];
    logits[o + 2] = a2 + b2[2];
    logits[o + 3] = a3 + b2[3];
  }
}

// softmax + recept.T + top-2 (ties: lower index) -> wsel[M,N]
__global__ void topk_kernel(const float* __restrict__ logits, const float* __restrict__ recept,
                            float* __restrict__ wsel, int Nn)
{
  int n = blockIdx.x * blockDim.x + threadIdx.x;
  if (n >= Nn) return;
  float l[4];
  #pragma unroll
  for (int m = 0; m < 4; ++m) l[m] = logits[(long long)n * 4 + m];
  float mx = fmaxf(fmaxf(l[0], l[1]), fmaxf(l[2], l[3]));
  float e[4], s = 0.f;
  #pragma unroll
  for (int m = 0; m < 4; ++m) { e[m] = expf(l[m] - mx); s += e[m]; }
  float sc[4];
  #pragma unroll
  for (int m = 0; m < 4; ++m) sc[m] = e[m] / s + recept[(long long)m * Nn + n];
  int i0 = 0; float v0 = sc[0];
  #pragma unroll
  for (int m = 1; m < 4; ++m) if (sc[m] > v0) { v0 = sc[m]; i0 = m; }
  int i1 = -1; float v1 = -INFINITY;
  #pragma unroll
  for (int m = 0; m < 4; ++m) { if (m == i0) continue; if (sc[m] > v1) { v1 = sc[m]; i1 = m; } }
  float ts = v0 + v1;
  float w0 = v0 / ts, w1 = v1 / ts;
  #pragma unroll
  for (int m = 0; m < 4; ++m)
    wsel[(long long)m * Nn + n] = (m == i0) ? w0 : ((m == i1) ? w1 : 0.f);
}

// compaction + record packed position per (m,n)
__global__ void compact_kernel(const float* __restrict__ wsel, int* __restrict__ idx,
                               int* __restrict__ posmn, int* __restrict__ cnts, int Nn)
{
  int n = blockIdx.x * blockDim.x + threadIdx.x;
  if (n >= Nn) return;
  #pragma unroll
  for (int m = 0; m < 4; ++m) {
    if (wsel[(long long)m * Nn + n] != 0.f) {
      int p = atomicAdd(&cnts[m], 1);
      idx[(long long)m * Nn + p] = n;
      posmn[(long long)m * Nn + n] = p;
    }
  }
}

__global__ void prefix4_kernel(const int* __restrict__ cnts, int* __restrict__ off)
{
  if (threadIdx.x == 0) {
    int r = 0;
    #pragma unroll
    for (int m = 0; m < 4; ++m) { off[m] = r; r += cnts[m]; }
  }
}

// final[n] = sum_m wsel[m,n] * outp[(expoff[m]+posmn[m,n])*128 + c]
__global__ void combine_kernel(const float* __restrict__ outp, const float* __restrict__ wsel,
                               const int* __restrict__ posmn, const int* __restrict__ expoff,
                               float* __restrict__ fin)
{
  long long i = (long long)blockIdx.x * blockDim.x + threadIdx.x;
  if (i >= (long long)N_ * 32) return;
  int n = (int)(i >> 5);
  int c4 = (int)(i & 31) * 4;
  float4 acc = make_float4(0.f, 0.f, 0.f, 0.f);
  #pragma unroll
  for (int m = 0; m < 4; ++m) {
    float w = wsel[(long long)m * N_ + n];
    if (w != 0.f) {
      int p = expoff[m] + posmn[(long long)m * N_ + n];
      float4 v = *(const float4*)(outp + (long long)p * 128 + c4);
      acc.x += w * v.x; acc.y += w * v.y; acc.z += w * v.z; acc.w += w * v.w;
    }
  }
  *(float4*)(fin + (long long)n * 128 + c4) = acc;
}

extern "C" void kernel_launch(void* const* d_in, const int* in_sizes, int n_in,
                              void* d_out, int out_size, void* d_ws, size_t ws_size,
                              hipStream_t stream) {
  const float* x_src   = (const float*)d_in[0];
  const float* x_dst   = (const float*)d_in[1];
  const int*   src_idx = (const int*)d_in[2];
  const int*   dst_idx = (const int*)d_in[3];
  const float* proj_Ws = (const float*)d_in[4];
  const float* proj_bs = (const float*)d_in[5];
  const float* projd_W = (const float*)d_in[6];
  const float* projd_b = (const float*)d_in[7];
  const float* lin_src = (const float*)d_in[8];
  const float* lin_dst = (const float*)d_in[9];
  const float* gm_W1   = (const float*)d_in[10];
  const float* gm_b1   = (const float*)d_in[11];
  const float* gm_W2   = (const float*)d_in[12];
  const float* gm_b2   = (const float*)d_in[13];
  const float* gate_W1 = (const float*)d_in[14];
  const float* gate_b1 = (const float*)d_in[15];
  const float* gate_W2 = (const float*)d_in[16];
  const float* gate_b2 = (const float*)d_in[17];
  const float* exp_W1  = (const float*)d_in[18];
  const float* exp_b1  = (const float*)d_in[19];
  const float* exp_W2  = (const float*)d_in[20];
  const float* exp_b2  = (const float*)d_in[21];
  float* final_out = (float*)d_out;

  float* ws = (float*)d_ws;
  float* bufA   = ws;                        // [M,N,128]: xs -> h1 -> gate-h -> packed expert-h
  float* bufB   = ws + 25600000LL;           // [M,N,128]: out1 ; later packed expert-out
  float* xd     = ws + 51200000LL;           // [N,128]
  float* asrc   = ws + 57600000LL;           // [M,N]
  float* adst   = ws + 57800000LL;           // [M,N]
  float* recept = ws + 58000000LL;           // [M,N]
  float* wsel   = ws + 58200000LL;           // [M,N]
  float* logits = ws + 58400000LL;           // [N,4]
  float* alpha  = ws + 58600000LL;           // [M,E]
  float* xdW1   = ws + 60200000LL;           // [N,128]
  float* zbuf   = ws + 66600000LL;           // [128] zeros
  int*   ibase  = (int*)(ws + 66700000LL);
  int*   rowptr = ibase;                     // [M,(N+1)]
  int*   col    = ibase + 200004;            // [M,E]
  int*   cnt    = ibase + 1800004;           // [M,N]
  int*   expidx = cnt;                       // reuse after CSR build
  int*   expcnt = ibase + 2000004;           // [4]
  int*   src_csr= ibase + 2000008;           // [M,E]
  int*   chunktot = ibase + 3600008;         // [M,64]
  int*   expoff = ibase + 3600264;           // [4]
  int*   posmn  = ibase + 3600268;           // [M,N]

  const long long NC = (long long)N_ * C_;
  const int RB = (N_ + 63) / 64;             // 782 row blocks
  const int NCH = (N_ + 1023) / 1024;        // 49

  // ---- CSR build ----
  hipMemsetAsync(cnt, 0, (size_t)M_ * N_ * sizeof(int), stream);
  hipMemsetAsync(zbuf, 0, 128 * sizeof(float), stream);
  count_kernel<<<dim3((E_ + 255) / 256, M_), 256, 0, stream>>>(dst_idx, cnt, N_);
  chunkscan_kernel<<<dim3(NCH, M_), 256, 0, stream>>>(cnt, rowptr, chunktot);
  scantot_kernel<<<1, 64, 0, stream>>>(chunktot, NCH);
  addoff_kernel<<<dim3(NCH, M_), 256, 0, stream>>>(rowptr, chunktot);
  hipMemsetAsync(cnt, 0, (size_t)M_ * N_ * sizeof(int), stream);
  scatter_kernel<<<dim3((E_ + 255) / 256, M_), 256, 0, stream>>>(dst_idx, rowptr, cnt, col, N_);
  sortbucket_kernel<<<dim3((N_ + 255) / 256, M_), 256, 0, stream>>>(rowptr, col, N_);

  // ---- xd = x_dst @ projd_W + b, with all 4 adst row-dots fused (EPI 11) ----
  gemm17<0, 11, 0><<<dim3(RB, 1, 1), 256, 0, stream>>>(
      x_dst, nullptr, projd_W, projd_b, xd, nullptr, nullptr, lin_dst, nullptr,
      nullptr, adst, N_, IN_, C_, 0, 0, 0, 0, 0);

  // ---- xdW1 = xd @ gm_W1 (zero bias) ----
  gemm17<0, 0, 0><<<dim3(RB, 1, 1), 256, 0, stream>>>(
      xd, nullptr, gm_W1, zbuf, xdW1, nullptr, nullptr, nullptr, nullptr,
      nullptr, nullptr, N_, C_, C_, 0, 0, 0, 0, 0);

  // ---- xs = per-type projection (batched) + fused a_src row-dot (EPI 10) ----
  gemm17<0, 10, 0><<<dim3(RB, M_, 1), 256, 0, stream>>>(
      x_src, nullptr, proj_Ws, proj_bs, bufA, nullptr, nullptr, lin_src, nullptr,
      nullptr, asrc, N_, IN_, C_, NC, (long long)IN_ * C_, C_, NC, 0);

  // ---- attention softmax (edge logit computed inline) ----
  alpha_kernel<<<dim3((N_ + 255) / 256, M_), 256, 0, stream>>>(
      rowptr, col, src_idx, asrc, adst, alpha, src_csr);

  // ---- propagation (single gather pass) -> out1 in bufB ----
  prop2_kernel<<<dim3((N_ + 1) / 2, M_), 256, 0, stream>>>(bufA, rowptr, alpha, src_csr, bufB);

  // ---- grad-map MLP: h1 = relu(out1@W1 + b1 - xdW1); fused W2 tail -> recept ----
  gemm17<0, 6, 0><<<dim3(RB, M_, 1), 256, 0, stream>>>(
      bufB, nullptr, gm_W1, gm_b1, bufA, nullptr, nullptr, nullptr, xdW1,
      nullptr, nullptr, N_, C_, C_, NC, 0, 0, NC, 0);
  gemm17<0, 5, 0><<<dim3(RB, M_, 1), 256, 0, stream>>>(
      bufA, xd, gm_W2, gm_b2, recept, nullptr, nullptr, nullptr, bufB,
      nullptr, nullptr, N_, C_, C_, NC, 0, 0, NC, 0);

  // ---- gate: h = relu(gate_in @ W1 + b1); feats fused on A-load ----
  gemm17<2, 1, 1><<<dim3(RB, 1, 2), 256, 0, stream>>>(
      bufB, nullptr, gate_W1, gate_b1, bufA, nullptr, nullptr, recept, nullptr,
      nullptr, nullptr, N_, M_ * C_, HID_, 0, 0, 0, 0, NC);
  gate_logits_kernel<<<dim3((N_ + 3) / 4), 256, 0, stream>>>(bufA, gate_W2, gate_b2, logits, N_);
  topk_kernel<<<(N_ + 255) / 256, 256, 0, stream>>>(logits, recept, wsel, N_);

  // ---- top-2 compaction + packed row offsets ----
  hipMemsetAsync(expcnt, 0, 4 * sizeof(int), stream);
  compact_kernel<<<(N_ + 255) / 256, 256, 0, stream>>>(wsel, expidx, posmn, expcnt, N_);
  prefix4_kernel<<<1, 64, 0, stream>>>(expcnt, expoff);

  // ---- experts: batched W1 (packed h in bufA), batched W2 (packed out), combine ----
  gemm17<4, 7, 2><<<dim3(RB, M_, 2), 256, 0, stream>>>(
      bufB, nullptr, exp_W1, exp_b1, bufA, expidx, expcnt, recept, nullptr,
      expoff, nullptr, N_, C_, HID_, NC, (long long)C_ * HID_, HID_, 0, 0);
  gemm17<5, 9, 0><<<dim3(RB, M_, 1), 256, 0, stream>>>(
      bufA, nullptr, exp_W2, exp_b2, bufB, expidx, expcnt, nullptr, nullptr,
      expoff, nullptr, N_, HID_, C_, 0, (long long)HID_ * C_, C_, 0, 0);
  combine_kernel<<<(int)(((long long)N_ * 32 + 255) / 256), 256, 0, stream>>>(
      bufB, wsel, posmn, expoff, final_out);
}